// Round 3
// baseline (299.616 us; speedup 1.0000x reference)
//
#include <hip/hip_runtime.h>

#define BLOCK 256
#define S_MAX 128
#define NV_MAX 729
#define NT_MAX 3072

// ---------------------------------------------------------------------------
// Kernel 1: per-ray first-hit over all triangles (Moller-Trumbore) in FULL
// FP64 (reference is numpy float64). First-index argmin tie-break.
// ---------------------------------------------------------------------------
__global__ __launch_bounds__(BLOCK) void isect_kernel(
    const float* __restrict__ verts,   // [NV*3] f32
    const float* __restrict__ ro,      // [R*3]  f32
    const float* __restrict__ rd,      // [R*3]  f32
    const int*   __restrict__ faces,   // [NF*3]
    double* __restrict__ tmin_out,     // [R]
    int*    __restrict__ fidx_out,     // [R]
    int NV, int NF)
{
    __shared__ float  sx[NV_MAX], sy[NV_MAX], sz[NV_MAX];
    __shared__ double rt[BLOCK];
    __shared__ int    ri[BLOCK];

    const int tid = threadIdx.x;
    for (int i = tid; i < NV; i += BLOCK) {
        sx[i] = verts[3 * i + 0];
        sy[i] = verts[3 * i + 1];
        sz[i] = verts[3 * i + 2];
    }
    __syncthreads();

    const int r = blockIdx.x;
    const double ox = (double)ro[3 * r + 0], oy = (double)ro[3 * r + 1], oz = (double)ro[3 * r + 2];
    const double dx = (double)rd[3 * r + 0], dy = (double)rd[3 * r + 1], dz = (double)rd[3 * r + 2];

    double bt = 1e10;
    int    bi = 0x7fffffff;

    for (int i = tid; i < NF; i += BLOCK) {
        const int i0 = faces[3 * i + 0];
        const int i1 = faces[3 * i + 1];
        const int i2 = faces[3 * i + 2];

        const double p0x = (double)sx[i0], p0y = (double)sy[i0], p0z = (double)sz[i0];
        const double e1x = (double)sx[i1] - p0x, e1y = (double)sy[i1] - p0y, e1z = (double)sz[i1] - p0z;
        const double e2x = (double)sx[i2] - p0x, e2y = (double)sy[i2] - p0y, e2z = (double)sz[i2] - p0z;

        // h = d x e2
        const double hx = dy * e2z - dz * e2y;
        const double hy = dz * e2x - dx * e2z;
        const double hz = dx * e2y - dy * e2x;
        const double a  = e1x * hx + e1y * hy + e1z * hz;
        const bool oka = fabs(a) > 1e-9;
        const double f  = 1.0 / (oka ? a : 1e-9);

        const double s0 = ox - p0x, s1 = oy - p0y, s2 = oz - p0z;
        const double u  = f * (s0 * hx + s1 * hy + s2 * hz);

        // q = s x e1
        const double qx = s1 * e1z - s2 * e1y;
        const double qy = s2 * e1x - s0 * e1z;
        const double qz = s0 * e1y - s1 * e1x;
        const double v  = f * (dx * qx + dy * qy + dz * qz);
        double t        = f * (e2x * qx + e2y * qy + e2z * qz);

        const bool ok = oka && (u >= 0.0) && (u <= 1.0) && (v >= 0.0) &&
                        (u + v <= 1.0) && (t > 1e-6);
        t = ok ? t : 1e10;

        if (t < bt || (t == bt && i < bi)) { bt = t; bi = i; }
    }

    rt[tid] = bt;
    ri[tid] = bi;
    __syncthreads();
    for (int s = BLOCK / 2; s > 0; s >>= 1) {
        if (tid < s) {
            const double t2 = rt[tid + s];
            const int    i2 = ri[tid + s];
            if (t2 < rt[tid] || (t2 == rt[tid] && i2 < ri[tid])) {
                rt[tid] = t2;
                ri[tid] = i2;
            }
        }
        __syncthreads();
    }
    if (tid == 0) {
        tmin_out[r] = rt[0];
        fidx_out[r] = ri[0];
    }
}

// ---------------------------------------------------------------------------
// Kernel 2: per-ray tet-walk sampling, FULL FP64 decision path.
// 3 walk iterations (compute-w, maybe-move) + final check, per sample.
// ---------------------------------------------------------------------------
__global__ __launch_bounds__(BLOCK) void trav_kernel(
    const float* __restrict__ verts,    // [NV*3] f32
    const float* __restrict__ ro,       // [R*3]  f32
    const float* __restrict__ rd,       // [R*3]  f32
    const int*   __restrict__ tetras,   // [NT*4]
    const int*   __restrict__ topo,     // [NT*4]
    const double* __restrict__ tmin_in, // [R]
    const int*    __restrict__ fidx_in, // [R]
    float* __restrict__ out_rayidx,     // [R*S]
    float* __restrict__ out_tetidx,     // [R*S]
    float* __restrict__ out_bary,       // [R*S*4]
    float* __restrict__ out_tstart,     // [R]
    float* __restrict__ out_tend,       // [R]
    float* __restrict__ out_pos,        // [R*S*3]
    int NV, int NT, int R)
{
    __shared__ float sx[NV_MAX], sy[NV_MAX], sz[NV_MAX];
    __shared__ int4  stet[NT_MAX];

    const int tid = threadIdx.x;
    for (int i = tid; i < NV; i += BLOCK) {
        sx[i] = verts[3 * i + 0];
        sy[i] = verts[3 * i + 1];
        sz[i] = verts[3 * i + 2];
    }
    const int4* t4 = (const int4*)tetras;
    for (int i = tid; i < NT; i += BLOCK) stet[i] = t4[i];
    __syncthreads();

    const int r = blockIdx.x * BLOCK + tid;
    if (r >= R) return;

    const double ox = (double)ro[3 * r + 0], oy = (double)ro[3 * r + 1], oz = (double)ro[3 * r + 2];
    const double dx = (double)rd[3 * r + 0], dy = (double)rd[3 * r + 1], dz = (double)rd[3 * r + 2];

    const double tmin = tmin_in[r];
    const int    fidx = fidx_in[r];
    const bool   hit  = tmin < 5.0;
    const double t0   = hit ? tmin : 0.0;

    const double hpx = ox + t0 * dx;
    const double hpy = oy + t0 * dy;
    const double hpz = oz + t0 * dz;

    int  tet   = hit ? (fidx >> 2) : 0;
    bool alive = hit;

    out_tstart[r] = (float)t0;
    out_tend[r]   = hit ? (float)(t0 + 0.05) : 0.0f;

    const double STEPD = 0.05 / 128.0;

    for (int k = 0; k < S_MAX; ++k) {
        const int base = r * S_MAX + k;

        if (!alive) {
            out_rayidx[base] = -1.0f;
            out_tetidx[base] = -1.0f;
            ((float4*)out_bary)[base] = make_float4(0.0f, 0.0f, 0.0f, 0.0f);
            out_pos[base * 3 + 0] = 0.0f;
            out_pos[base * 3 + 1] = 0.0f;
            out_pos[base * 3 + 2] = 0.0f;
            continue;
        }

        const double toff = (double)k * STEPD + 1e-4;
        const double px = hpx + toff * dx;
        const double py = hpy + toff * dy;
        const double pz = hpz + toff * dz;

        bool   inside = false;
        double w0 = 0.0, w1 = 0.0, w2 = 0.0, w3 = 0.0;

        for (int it = 0; it < 4; ++it) {
            const int4 tv = stet[tet];
            const double v0x = (double)sx[tv.x], v0y = (double)sy[tv.x], v0z = (double)sz[tv.x];

            const double m11 = (double)sx[tv.y] - v0x, m21 = (double)sy[tv.y] - v0y, m31 = (double)sz[tv.y] - v0z;
            const double m12 = (double)sx[tv.z] - v0x, m22 = (double)sy[tv.z] - v0y, m32 = (double)sz[tv.z] - v0z;
            const double m13 = (double)sx[tv.w] - v0x, m23 = (double)sy[tv.w] - v0y, m33 = (double)sz[tv.w] - v0z;
            const double b1 = px - v0x, b2 = py - v0y, b3 = pz - v0z;

            // FP64 Cramer solve of [c1 c2 c3] w = b  (vs ref dgesv: ~1e-15 agreement)
            const double A = m22 * m33 - m23 * m32;
            const double B = m21 * m33 - m23 * m31;
            const double C = m21 * m32 - m22 * m31;
            const double det = m11 * A - m12 * B + m13 * C;
            const double inv = 1.0 / det;

            w1 = (b1 * A - m12 * (b2 * m33 - m23 * b3) + m13 * (b2 * m32 - m22 * b3)) * inv;
            w2 = (m11 * (b2 * m33 - m23 * b3) - b1 * B + m13 * (m21 * b3 - b2 * m31)) * inv;
            w3 = (m11 * (m22 * b3 - b2 * m32) - m12 * (m21 * b3 - b2 * m31) + b1 * C) * inv;
            w0 = 1.0 - (w1 + w2 + w3);

            inside = (w0 >= -1e-6) && (w1 >= -1e-6) && (w2 >= -1e-6) && (w3 >= -1e-6);
            if (inside) break;
            if (it == 3) break;   // 4th compute is the final check, no move

            // first-occurrence argmin over (w0,w1,w2,w3)
            int    jm = 0;
            double wb = w0;
            if (w1 < wb) { wb = w1; jm = 1; }
            if (w2 < wb) { wb = w2; jm = 2; }
            if (w3 < wb) { wb = w3; jm = 3; }

            const int nb = topo[tet * 4 + (3 - jm)];
            if (nb >= 0) {
                tet = nb;
            } else {
                alive = false;
                break;
            }
        }

        const bool  valid = alive && inside;
        const float m = valid ? 1.0f : 0.0f;
        out_rayidx[base] = valid ? (float)r : -1.0f;
        out_tetidx[base] = valid ? (float)tet : -1.0f;
        ((float4*)out_bary)[base] = make_float4((float)w0 * m, (float)w1 * m, (float)w2 * m, (float)w3 * m);
        out_pos[base * 3 + 0] = (float)px * m;
        out_pos[base * 3 + 1] = (float)py * m;
        out_pos[base * 3 + 2] = (float)pz * m;
    }
}

extern "C" void kernel_launch(void* const* d_in, const int* in_sizes, int n_in,
                              void* d_out, int out_size, void* d_ws, size_t ws_size,
                              hipStream_t stream) {
    const float* verts  = (const float*)d_in[0];  // (1, 729, 3) f32
    const float* ro     = (const float*)d_in[1];  // (1, R, 3)   f32
    const float* rd     = (const float*)d_in[2];  // (1, R, 3)   f32
    const int*   tetras = (const int*)d_in[3];    // (NT, 4)     i32
    const int*   faces  = (const int*)d_in[4];    // (NT, 4, 3)  i32
    const int*   topo   = (const int*)d_in[5];    // (NT, 4)     i32

    const int NV = in_sizes[0] / 3;
    const int R  = in_sizes[1] / 3;
    const int NT = in_sizes[3] / 4;
    const int NF = in_sizes[4] / 3;
    const int S  = S_MAX;

    // workspace: per-ray tmin (double) + fidx (int)
    double* wtmin = (double*)d_ws;
    int*    wfidx = (int*)(wtmin + R);

    // output layout (flat float32, reference return order)
    float* out        = (float*)d_out;
    float* out_rayidx = out;                      // R*S
    float* out_tetidx = out + (size_t)R * S;      // R*S
    float* out_bary   = out + (size_t)2 * R * S;  // R*S*4
    float* out_tstart = out + (size_t)6 * R * S;  // R
    float* out_tend   = out_tstart + R;           // R
    float* out_pos    = out_tend + R;             // R*S*3

    isect_kernel<<<R, BLOCK, 0, stream>>>(verts, ro, rd, faces, wtmin, wfidx, NV, NF);
    trav_kernel<<<(R + BLOCK - 1) / BLOCK, BLOCK, 0, stream>>>(
        verts, ro, rd, tetras, topo, wtmin, wfidx,
        out_rayidx, out_tetidx, out_bary, out_tstart, out_tend, out_pos,
        NV, NT, R);
}

// Round 4
// 204.676 us; speedup vs baseline: 1.4639x; 1.4639x over previous
//
#include <hip/hip_runtime.h>

#define BLOCK 256
#define BLOCK_T 64
#define S_MAX 128
#define NV_MAX 729
#define FACES_PER_SLAB 1536   // 64 (i,j) pairs * 6 tets * 4 faces
#define EPS_L 2e-3f           // loose/strict u,v,t band (f32 err <= ~3e-4 at |a|>=1e-3)
#define FORCE_A 1e-3f         // |a32| below this -> always f64 (1/a error amplification)
#define BAND 4e-3f            // t band around strict-f32 min

// ---------------------------------------------------------------------------
// Kernel 1: per-ray first hit. f32 prefilter with conservative bands +
// geometric z-slab culling; exact-f64 (round-3-identical) refine of the few
// candidates; first-index argmin tie-break.
// Slab decode: face F -> tet = F>>2 -> k = (tet/6) % 8 ; faces of slab k for
// (i,j)=ij are the 24 contiguous faces at F = ij*192 + k*24.
// ---------------------------------------------------------------------------
__global__ __launch_bounds__(BLOCK) void isect_kernel(
    const float* __restrict__ verts,   // [NV*3] f32
    const float* __restrict__ ro,      // [R*3]  f32
    const float* __restrict__ rd,      // [R*3]  f32
    const int*   __restrict__ faces,   // [NF*3]
    double* __restrict__ tmin_out,     // [R]
    int*    __restrict__ fidx_out,     // [R]
    int NV, int NF)
{
    __shared__ float sx[NV_MAX], sy[NV_MAX], sz[NV_MAX];
    __shared__ float s_vmin[9];     // min z per grid k-index
    __shared__ float s_slabz[8];    // min z over slab k's vertices
    __shared__ float s_bt;          // block strict-f32 min t
    __shared__ float  s_rf[4];
    __shared__ double s_rt[4];
    __shared__ int    s_ri[4];

    const int tid = threadIdx.x;
    for (int i = tid; i < NV; i += BLOCK) {
        sx[i] = verts[3 * i + 0];
        sy[i] = verts[3 * i + 1];
        sz[i] = verts[3 * i + 2];
    }
    __syncthreads();
    if (tid < 9) {                  // vid = 9*m + kv  (kv = z index)
        float m = 1e9f;
        for (int q = 0; q < 81; ++q) m = fminf(m, sz[q * 9 + tid]);
        s_vmin[tid] = m;
    }
    if (tid == 0) s_bt = 1e10f;
    __syncthreads();
    if (tid < 8) s_slabz[tid] = fminf(s_vmin[tid], s_vmin[tid + 1]);
    __syncthreads();

    const int r = blockIdx.x;
    const float oxf = ro[3 * r + 0], oyf = ro[3 * r + 1], ozf = ro[3 * r + 2];
    const float dxf = rd[3 * r + 0], dyf = rd[3 * r + 1], dzf = rd[3 * r + 2];

    // ---------------- phase 1: f32 strict min (upper bound on true min t) ---
    float bt_strict = 1e10f;
    for (int ks = 0; ks < 8; ++ks) {
        if (ks > 0 && dzf > 0.0f) {
            const float zcut = ozf + (s_bt + BAND) * dzf;
            if (s_slabz[ks] > zcut) continue;     // uniform: sound geometric cull
        }
        for (int s = tid; s < FACES_PER_SLAB; s += BLOCK) {
            const int ij = s / 24;
            const int F  = ij * 192 + ks * 24 + (s - ij * 24);
            const int i0 = faces[3 * F + 0];
            const int i1 = faces[3 * F + 1];
            const int i2 = faces[3 * F + 2];

            const float p0x = sx[i0], p0y = sy[i0], p0z = sz[i0];
            const float e1x = sx[i1] - p0x, e1y = sy[i1] - p0y, e1z = sz[i1] - p0z;
            const float e2x = sx[i2] - p0x, e2y = sy[i2] - p0y, e2z = sz[i2] - p0z;
            const float hx = dyf * e2z - dzf * e2y;
            const float hy = dzf * e2x - dxf * e2z;
            const float hz = dxf * e2y - dyf * e2x;
            const float a  = e1x * hx + e1y * hy + e1z * hz;
            const float af = fabsf(a);
            if (af <= FORCE_A) continue;          // unreliable -> f64 handles in refine
            const float f = 1.0f / a;
            const float s0 = oxf - p0x, s1 = oyf - p0y, s2 = ozf - p0z;
            const float u  = f * (s0 * hx + s1 * hy + s2 * hz);
            const float qx = s1 * e1z - s2 * e1y;
            const float qy = s2 * e1x - s0 * e1z;
            const float qz = s0 * e1y - s1 * e1x;
            const float v  = f * (dxf * qx + dyf * qy + dzf * qz);
            const float t  = f * (e2x * qx + e2y * qy + e2z * qz);
            const bool strict = (u >= EPS_L) && (u <= 1.0f - EPS_L) &&
                                (v >= EPS_L) && (u + v <= 1.0f - EPS_L) &&
                                (t > 1e-6f + EPS_L);
            if (strict) bt_strict = fminf(bt_strict, t);
        }
        // block-reduce running strict min -> s_bt
        float w = bt_strict;
        for (int off = 32; off; off >>= 1) w = fminf(w, __shfl_down(w, off));
        if ((tid & 63) == 0) s_rf[tid >> 6] = w;
        __syncthreads();
        if (tid == 0) s_bt = fminf(fminf(s_rf[0], s_rf[1]), fminf(s_rf[2], s_rf[3]));
        __syncthreads();
    }

    // ---------------- phase 2: f64 refine of banded/forced candidates -------
    const double ox = (double)oxf, oy = (double)oyf, oz = (double)ozf;
    const double dx = (double)dxf, dy = (double)dyf, dz = (double)dzf;
    double bt = 1e10;
    int    bi = 0x7fffffff;

    for (int ks = 0; ks < 8; ++ks) {
        if (ks > 0 && dzf > 0.0f) {
            const float zcut = ozf + (s_bt + BAND) * dzf;
            if (s_slabz[ks] > zcut) continue;
        }
        for (int s = tid; s < FACES_PER_SLAB; s += BLOCK) {
            const int ij = s / 24;
            const int F  = ij * 192 + ks * 24 + (s - ij * 24);
            const int i0 = faces[3 * F + 0];
            const int i1 = faces[3 * F + 1];
            const int i2 = faces[3 * F + 2];

            const float p0xf = sx[i0], p0yf = sy[i0], p0zf = sz[i0];
            const float e1xf = sx[i1] - p0xf, e1yf = sy[i1] - p0yf, e1zf = sz[i1] - p0zf;
            const float e2xf = sx[i2] - p0xf, e2yf = sy[i2] - p0yf, e2zf = sz[i2] - p0zf;
            const float hxf = dyf * e2zf - dzf * e2yf;
            const float hyf = dzf * e2xf - dxf * e2zf;
            const float hzf = dxf * e2yf - dyf * e2xf;
            const float af32 = e1xf * hxf + e1yf * hyf + e1zf * hzf;
            const float afab = fabsf(af32);

            bool cand = (afab <= FORCE_A);
            if (!cand) {
                const float ff = 1.0f / af32;
                const float s0f = oxf - p0xf, s1f = oyf - p0yf, s2f = ozf - p0zf;
                const float uf  = ff * (s0f * hxf + s1f * hyf + s2f * hzf);
                const float qxf = s1f * e1zf - s2f * e1yf;
                const float qyf = s2f * e1xf - s0f * e1zf;
                const float qzf = s0f * e1yf - s1f * e1xf;
                const float vf  = ff * (dxf * qxf + dyf * qyf + dzf * qzf);
                const float tf  = ff * (e2xf * qxf + e2yf * qyf + e2zf * qzf);
                cand = (uf >= -EPS_L) && (uf <= 1.0f + EPS_L) &&
                       (vf >= -EPS_L) && (uf + vf <= 1.0f + EPS_L) &&
                       (tf > 1e-6f - EPS_L) && (tf <= s_bt + BAND);
            }
            if (!cand) continue;

            // exact f64 evaluation (identical to the round-3 passing kernel)
            const double p0x = (double)sx[i0], p0y = (double)sy[i0], p0z = (double)sz[i0];
            const double e1x = (double)sx[i1] - p0x, e1y = (double)sy[i1] - p0y, e1z = (double)sz[i1] - p0z;
            const double e2x = (double)sx[i2] - p0x, e2y = (double)sy[i2] - p0y, e2z = (double)sz[i2] - p0z;
            const double hx = dy * e2z - dz * e2y;
            const double hy = dz * e2x - dx * e2z;
            const double hz = dx * e2y - dy * e2x;
            const double a  = e1x * hx + e1y * hy + e1z * hz;
            const bool oka = fabs(a) > 1e-9;
            const double f  = 1.0 / (oka ? a : 1e-9);
            const double s0 = ox - p0x, s1 = oy - p0y, s2 = oz - p0z;
            const double u  = f * (s0 * hx + s1 * hy + s2 * hz);
            const double qx = s1 * e1z - s2 * e1y;
            const double qy = s2 * e1x - s0 * e1z;
            const double qz = s0 * e1y - s1 * e1x;
            const double v  = f * (dx * qx + dy * qy + dz * qz);
            double t        = f * (e2x * qx + e2y * qy + e2z * qz);
            const bool ok = oka && (u >= 0.0) && (u <= 1.0) && (v >= 0.0) &&
                            (u + v <= 1.0) && (t > 1e-6);
            t = ok ? t : 1e10;
            if (t < bt || (t == bt && F < bi)) { bt = t; bi = F; }
        }
    }

    // final (t, idx) reduce, first-index tie-break
    for (int off = 32; off; off >>= 1) {
        const double t2 = __shfl_down(bt, off);
        const int    i2 = __shfl_down(bi, off);
        if (t2 < bt || (t2 == bt && i2 < bi)) { bt = t2; bi = i2; }
    }
    if ((tid & 63) == 0) { s_rt[tid >> 6] = bt; s_ri[tid >> 6] = bi; }
    __syncthreads();
    if (tid == 0) {
        for (int w = 1; w < 4; ++w) {
            if (s_rt[w] < bt || (s_rt[w] == bt && s_ri[w] < bi)) { bt = s_rt[w]; bi = s_ri[w]; }
        }
        tmin_out[r] = bt;
        fidx_out[r] = bi;
    }
}

// ---------------------------------------------------------------------------
// Kernel 2: per-ray tet-walk sampling, f64 decisions, cached inverse.
// ---------------------------------------------------------------------------
__device__ __forceinline__ void build_inv(
    int tet, const int4* __restrict__ t4,
    const float* sx, const float* sy, const float* sz,
    double& v0x, double& v0y, double& v0z, double inv[9])
{
    const int4 tv = t4[tet];
    v0x = (double)sx[tv.x]; v0y = (double)sy[tv.x]; v0z = (double)sz[tv.x];
    const double m11 = (double)sx[tv.y] - v0x, m21 = (double)sy[tv.y] - v0y, m31 = (double)sz[tv.y] - v0z;
    const double m12 = (double)sx[tv.z] - v0x, m22 = (double)sy[tv.z] - v0y, m32 = (double)sz[tv.z] - v0z;
    const double m13 = (double)sx[tv.w] - v0x, m23 = (double)sy[tv.w] - v0y, m33 = (double)sz[tv.w] - v0z;
    const double A = m22 * m33 - m23 * m32;
    const double B = m21 * m33 - m23 * m31;
    const double C = m21 * m32 - m22 * m31;
    const double det = m11 * A - m12 * B + m13 * C;
    const double rcp = 1.0 / det;
    inv[0] = A * rcp;                      inv[1] = (m13 * m32 - m12 * m33) * rcp;  inv[2] = (m12 * m23 - m13 * m22) * rcp;
    inv[3] = -B * rcp;                     inv[4] = (m11 * m33 - m13 * m31) * rcp;  inv[5] = (m13 * m21 - m11 * m23) * rcp;
    inv[6] = C * rcp;                      inv[7] = (m12 * m31 - m11 * m32) * rcp;  inv[8] = (m11 * m22 - m12 * m21) * rcp;
}

__global__ __launch_bounds__(BLOCK_T) void trav_kernel(
    const float* __restrict__ verts,    // [NV*3] f32
    const float* __restrict__ ro,       // [R*3]  f32
    const float* __restrict__ rd,       // [R*3]  f32
    const int*   __restrict__ tetras,   // [NT*4]
    const int*   __restrict__ topo,     // [NT*4]
    const double* __restrict__ tmin_in, // [R]
    const int*    __restrict__ fidx_in, // [R]
    float* __restrict__ out_rayidx,     // [R*S]
    float* __restrict__ out_tetidx,     // [R*S]
    float* __restrict__ out_bary,       // [R*S*4]
    float* __restrict__ out_tstart,     // [R]
    float* __restrict__ out_tend,       // [R]
    float* __restrict__ out_pos,        // [R*S*3]
    int NV, int R)
{
    __shared__ float sx[NV_MAX], sy[NV_MAX], sz[NV_MAX];
    const int tid = threadIdx.x;
    for (int i = tid; i < NV; i += BLOCK_T) {
        sx[i] = verts[3 * i + 0];
        sy[i] = verts[3 * i + 1];
        sz[i] = verts[3 * i + 2];
    }
    __syncthreads();

    const int r = blockIdx.x * BLOCK_T + tid;
    if (r >= R) return;

    const int4* t4 = (const int4*)tetras;

    const double ox = (double)ro[3 * r + 0], oy = (double)ro[3 * r + 1], oz = (double)ro[3 * r + 2];
    const double dx = (double)rd[3 * r + 0], dy = (double)rd[3 * r + 1], dz = (double)rd[3 * r + 2];

    const double tmin = tmin_in[r];
    const int    fidx = fidx_in[r];
    const bool   hit  = tmin < 5.0;
    const double t0   = hit ? tmin : 0.0;

    const double hpx = ox + t0 * dx;
    const double hpy = oy + t0 * dy;
    const double hpz = oz + t0 * dz;

    int  tet   = hit ? (fidx >> 2) : 0;
    bool alive = hit;

    out_tstart[r] = (float)t0;
    out_tend[r]   = hit ? (float)(t0 + 0.05) : 0.0f;

    double v0x = 0.0, v0y = 0.0, v0z = 0.0;
    double inv[9];
    if (alive) build_inv(tet, t4, sx, sy, sz, v0x, v0y, v0z, inv);

    const double STEPD = 0.05 / 128.0;

    for (int k = 0; k < S_MAX; ++k) {
        const int base = r * S_MAX + k;

        if (!alive) {
            out_rayidx[base] = -1.0f;
            out_tetidx[base] = -1.0f;
            ((float4*)out_bary)[base] = make_float4(0.0f, 0.0f, 0.0f, 0.0f);
            out_pos[base * 3 + 0] = 0.0f;
            out_pos[base * 3 + 1] = 0.0f;
            out_pos[base * 3 + 2] = 0.0f;
            continue;
        }

        const double toff = (double)k * STEPD + 1e-4;
        const double px = hpx + toff * dx;
        const double py = hpy + toff * dy;
        const double pz = hpz + toff * dz;

        double b1 = px - v0x, b2 = py - v0y, b3 = pz - v0z;
        double w1 = inv[0] * b1 + inv[1] * b2 + inv[2] * b3;
        double w2 = inv[3] * b1 + inv[4] * b2 + inv[5] * b3;
        double w3 = inv[6] * b1 + inv[7] * b2 + inv[8] * b3;
        double w0 = 1.0 - (w1 + w2 + w3);
        bool inside = (w0 >= -1e-6) && (w1 >= -1e-6) && (w2 >= -1e-6) && (w3 >= -1e-6);

        // ref: up to 3 moves, each followed by a fresh bary evaluation.
        int it = 0;
        while (!inside && it < 3) {
            int    jm = 0;
            double wb = w0;
            if (w1 < wb) { wb = w1; jm = 1; }
            if (w2 < wb) { wb = w2; jm = 2; }
            if (w3 < wb) { wb = w3; jm = 3; }
            const int nb = topo[tet * 4 + (3 - jm)];
            if (nb < 0) { alive = false; break; }
            tet = nb;
            build_inv(tet, t4, sx, sy, sz, v0x, v0y, v0z, inv);
            b1 = px - v0x; b2 = py - v0y; b3 = pz - v0z;
            w1 = inv[0] * b1 + inv[1] * b2 + inv[2] * b3;
            w2 = inv[3] * b1 + inv[4] * b2 + inv[5] * b3;
            w3 = inv[6] * b1 + inv[7] * b2 + inv[8] * b3;
            w0 = 1.0 - (w1 + w2 + w3);
            inside = (w0 >= -1e-6) && (w1 >= -1e-6) && (w2 >= -1e-6) && (w3 >= -1e-6);
            ++it;
        }

        const bool  valid = alive && inside;
        const float m = valid ? 1.0f : 0.0f;
        out_rayidx[base] = valid ? (float)r : -1.0f;
        out_tetidx[base] = valid ? (float)tet : -1.0f;
        ((float4*)out_bary)[base] = make_float4((float)w0 * m, (float)w1 * m, (float)w2 * m, (float)w3 * m);
        out_pos[base * 3 + 0] = (float)px * m;
        out_pos[base * 3 + 1] = (float)py * m;
        out_pos[base * 3 + 2] = (float)pz * m;
    }
}

extern "C" void kernel_launch(void* const* d_in, const int* in_sizes, int n_in,
                              void* d_out, int out_size, void* d_ws, size_t ws_size,
                              hipStream_t stream) {
    const float* verts  = (const float*)d_in[0];  // (1, 729, 3) f32
    const float* ro     = (const float*)d_in[1];  // (1, R, 3)   f32
    const float* rd     = (const float*)d_in[2];  // (1, R, 3)   f32
    const int*   tetras = (const int*)d_in[3];    // (NT, 4)     i32
    const int*   faces  = (const int*)d_in[4];    // (NT, 4, 3)  i32
    const int*   topo   = (const int*)d_in[5];    // (NT, 4)     i32

    const int NV = in_sizes[0] / 3;
    const int R  = in_sizes[1] / 3;
    const int NF = in_sizes[4] / 3;
    const int S  = S_MAX;

    double* wtmin = (double*)d_ws;
    int*    wfidx = (int*)(wtmin + R);

    float* out        = (float*)d_out;
    float* out_rayidx = out;                      // R*S
    float* out_tetidx = out + (size_t)R * S;      // R*S
    float* out_bary   = out + (size_t)2 * R * S;  // R*S*4
    float* out_tstart = out + (size_t)6 * R * S;  // R
    float* out_tend   = out_tstart + R;           // R
    float* out_pos    = out_tend + R;             // R*S*3

    isect_kernel<<<R, BLOCK, 0, stream>>>(verts, ro, rd, faces, wtmin, wfidx, NV, NF);
    trav_kernel<<<(R + BLOCK_T - 1) / BLOCK_T, BLOCK_T, 0, stream>>>(
        verts, ro, rd, tetras, topo, wtmin, wfidx,
        out_rayidx, out_tetidx, out_bary, out_tstart, out_tend, out_pos,
        NV, R);
}

// Round 5
// 146.868 us; speedup vs baseline: 2.0400x; 1.3936x over previous
//
#include <hip/hip_runtime.h>

#define S_MAX 128
#define NV_MAX 729
#define STEPD (0.05 / 128.0)

// ---------------------------------------------------------------------------
// Exact f64 Moller-Trumbore for face F (identical expressions to the round-3
// passing kernel). Returns t or 1e10.
// ---------------------------------------------------------------------------
static __device__ __forceinline__ double mt_eval_f64(
    int F, const int* __restrict__ faces,
    const float* sx, const float* sy, const float* sz,
    double ox, double oy, double oz,
    double dx, double dy, double dz)
{
    const int i0 = faces[3 * F + 0];
    const int i1 = faces[3 * F + 1];
    const int i2 = faces[3 * F + 2];
    const double p0x = (double)sx[i0], p0y = (double)sy[i0], p0z = (double)sz[i0];
    const double e1x = (double)sx[i1] - p0x, e1y = (double)sy[i1] - p0y, e1z = (double)sz[i1] - p0z;
    const double e2x = (double)sx[i2] - p0x, e2y = (double)sy[i2] - p0y, e2z = (double)sz[i2] - p0z;
    const double hx = dy * e2z - dz * e2y;
    const double hy = dz * e2x - dx * e2z;
    const double hz = dx * e2y - dy * e2x;
    const double a  = e1x * hx + e1y * hy + e1z * hz;
    const bool oka = fabs(a) > 1e-9;
    const double f  = 1.0 / (oka ? a : 1e-9);
    const double s0 = ox - p0x, s1 = oy - p0y, s2 = oz - p0z;
    const double u  = f * (s0 * hx + s1 * hy + s2 * hz);
    const double qx = s1 * e1z - s2 * e1y;
    const double qy = s2 * e1x - s0 * e1z;
    const double qz = s0 * e1y - s1 * e1x;
    const double v  = f * (dx * qx + dy * qy + dz * qz);
    double t        = f * (e2x * qx + e2y * qy + e2z * qz);
    const bool ok = oka && (u >= 0.0) && (u <= 1.0) && (v >= 0.0) &&
                    (u + v <= 1.0) && (t > 1e-6);
    return ok ? t : 1e10;
}

// ---------------------------------------------------------------------------
// Kernel 1: first hit. One wave per ray. Candidate set = 24 faces per k=0
// cell overlapping the ray's xy-track over [zmin0, zmax0] (+ measured jitter
// margin) — sound cover of the global argmin (see session notes). All
// candidates evaluated in exact f64; (t, F) lexicographic wave reduce.
// Never-taken full-scan fallback guards the cover argument.
// ---------------------------------------------------------------------------
__global__ __launch_bounds__(256) void isect_kernel(
    const float* __restrict__ verts,   // [NV*3] f32
    const float* __restrict__ ro,      // [R*3]  f32
    const float* __restrict__ rd,      // [R*3]  f32
    const int*   __restrict__ faces,   // [NF*3]
    double* __restrict__ tmin_out,     // [R]
    int*    __restrict__ fidx_out,     // [R]
    int NV, int NF, int R)
{
    __shared__ float sx[NV_MAX], sy[NV_MAX], sz[NV_MAX];
    __shared__ float red[256];
    __shared__ float s_zmin, s_zmax, s_marg;

    const int tid = threadIdx.x;
    for (int i = tid; i < NV; i += 256) {
        sx[i] = verts[3 * i + 0];
        sy[i] = verts[3 * i + 1];
        sz[i] = verts[3 * i + 2];
    }
    __syncthreads();

    // data-driven bounds: layer-0 z range, max xy jitter deviation
    float zmin = 1e9f, zmax = -1e9f, dev = 0.0f;
    for (int i = tid; i < NV; i += 256) {
        const float z = sz[i];
        if (i % 9 == 0) { zmin = fminf(zmin, z); zmax = fmaxf(zmax, z); }
        const float x = sx[i], y = sy[i];
        dev = fmaxf(dev, fabsf(x - rintf(x * 8.0f) * 0.125f));
        dev = fmaxf(dev, fabsf(y - rintf(y * 8.0f) * 0.125f));
    }
    red[tid] = zmin; __syncthreads();
    for (int s = 128; s; s >>= 1) { if (tid < s) red[tid] = fminf(red[tid], red[tid + s]); __syncthreads(); }
    if (tid == 0) s_zmin = red[0];
    __syncthreads();
    red[tid] = zmax; __syncthreads();
    for (int s = 128; s; s >>= 1) { if (tid < s) red[tid] = fmaxf(red[tid], red[tid + s]); __syncthreads(); }
    if (tid == 0) s_zmax = red[0];
    __syncthreads();
    red[tid] = dev; __syncthreads();
    for (int s = 128; s; s >>= 1) { if (tid < s) red[tid] = fmaxf(red[tid], red[tid + s]); __syncthreads(); }
    if (tid == 0) s_marg = red[0] + 1e-5f;
    __syncthreads();

    const int wv = tid >> 6, lane = tid & 63;
    const int r = blockIdx.x * 4 + wv;
    if (r >= R) return;

    const double ox = (double)ro[3 * r + 0], oy = (double)ro[3 * r + 1], oz = (double)ro[3 * r + 2];
    const double dx = (double)rd[3 * r + 0], dy = (double)rd[3 * r + 1], dz = (double)rd[3 * r + 2];

    int ncand = 0, ixlo = 0, iylo = 0, nx = 0, ny = 1;
    if (dz > 0.0) {
        const double t_lo = ((double)s_zmin - oz) / dz;
        const double t_hi = ((double)s_zmax - oz) / dz;
        const double marg = (double)s_marg + 1e-9;
        const double xa = ox + t_lo * dx, xb = ox + t_hi * dx;
        const double ya = oy + t_lo * dy, yb = oy + t_hi * dy;
        const double xlo = fmin(xa, xb) - marg, xhi = fmax(xa, xb) + marg;
        const double ylo = fmin(ya, yb) - marg, yhi = fmax(ya, yb) + marg;
        const int ix0 = max(0, (int)floor(xlo * 8.0)), ix1 = min(7, (int)floor(xhi * 8.0));
        const int iy0 = max(0, (int)floor(ylo * 8.0)), iy1 = min(7, (int)floor(yhi * 8.0));
        if (ix0 <= ix1 && iy0 <= iy1) {
            ixlo = ix0; iylo = iy0;
            nx = ix1 - ix0 + 1; ny = iy1 - iy0 + 1;
            ncand = nx * ny * 24;
        }
    }

    double bt = 1e10;
    int    bi = 0x7fffffff;
    for (int c = lane; c < ncand; c += 64) {
        const int cell = c / 24, fk = c - cell * 24;
        const int cx = cell / ny, cy = cell - cx * ny;
        const int F = ((ixlo + cx) * 64 + (iylo + cy) * 8) * 24 + fk;
        const double t = mt_eval_f64(F, faces, sx, sy, sz, ox, oy, oz, dx, dy, dz);
        if (t < bt || (t == bt && F < bi)) { bt = t; bi = F; }
    }
    for (int off = 32; off; off >>= 1) {
        const double t2 = __shfl_down(bt, off);
        const int    i2 = __shfl_down(bi, off);
        if (t2 < bt || (t2 == bt && i2 < bi)) { bt = t2; bi = i2; }
    }
    // fallback (wave-uniform, never taken in practice): full scan
    const double btw = __shfl(bt, 0);
    if (btw >= 1e10) {
        bt = 1e10; bi = 0x7fffffff;
        for (int F = lane; F < NF; F += 64) {
            const double t = mt_eval_f64(F, faces, sx, sy, sz, ox, oy, oz, dx, dy, dz);
            if (t < bt || (t == bt && F < bi)) { bt = t; bi = F; }
        }
        for (int off = 32; off; off >>= 1) {
            const double t2 = __shfl_down(bt, off);
            const int    i2 = __shfl_down(bi, off);
            if (t2 < bt || (t2 == bt && i2 < bi)) { bt = t2; bi = i2; }
        }
    }
    if (lane == 0) { tmin_out[r] = bt; fidx_out[r] = bi; }
}

// ---------------------------------------------------------------------------
// Cached-inverse builder (round-4-identical).
// ---------------------------------------------------------------------------
static __device__ __forceinline__ void build_inv(
    int tet, const int4* __restrict__ t4,
    const float* sx, const float* sy, const float* sz,
    double& v0x, double& v0y, double& v0z, double inv[9])
{
    const int4 tv = t4[tet];
    v0x = (double)sx[tv.x]; v0y = (double)sy[tv.x]; v0z = (double)sz[tv.x];
    const double m11 = (double)sx[tv.y] - v0x, m21 = (double)sy[tv.y] - v0y, m31 = (double)sz[tv.y] - v0z;
    const double m12 = (double)sx[tv.z] - v0x, m22 = (double)sy[tv.z] - v0y, m32 = (double)sz[tv.z] - v0z;
    const double m13 = (double)sx[tv.w] - v0x, m23 = (double)sy[tv.w] - v0y, m33 = (double)sz[tv.w] - v0z;
    const double A = m22 * m33 - m23 * m32;
    const double B = m21 * m33 - m23 * m31;
    const double C = m21 * m32 - m22 * m31;
    const double det = m11 * A - m12 * B + m13 * C;
    const double rcp = 1.0 / det;
    inv[0] = A * rcp;  inv[1] = (m13 * m32 - m12 * m33) * rcp;  inv[2] = (m12 * m23 - m13 * m22) * rcp;
    inv[3] = -B * rcp; inv[4] = (m11 * m33 - m13 * m31) * rcp;  inv[5] = (m13 * m21 - m11 * m23) * rcp;
    inv[6] = C * rcp;  inv[7] = (m12 * m31 - m11 * m32) * rcp;  inv[8] = (m11 * m22 - m12 * m21) * rcp;
}

// ---------------------------------------------------------------------------
// Kernel 2 (serial decisions): per-ray tet chain. Affine-in-toff w fast path;
// exact round-4 matvec + <=3-move walk on boundary-adjacent samples.
// Emits per-sample tet (int16, -1 = invalid) + t_start/t_end.
// ---------------------------------------------------------------------------
__global__ __launch_bounds__(64) void walk_kernel(
    const float* __restrict__ verts,
    const float* __restrict__ ro,
    const float* __restrict__ rd,
    const int*   __restrict__ tetras,
    const int*   __restrict__ topo,
    const double* __restrict__ tmin_in,
    const int*    __restrict__ fidx_in,
    short* __restrict__ seq,            // [R*S]
    float* __restrict__ out_tstart,     // [R]
    float* __restrict__ out_tend,       // [R]
    int NV, int R)
{
    __shared__ float sx[NV_MAX], sy[NV_MAX], sz[NV_MAX];
    const int tid = threadIdx.x;
    for (int i = tid; i < NV; i += 64) {
        sx[i] = verts[3 * i + 0];
        sy[i] = verts[3 * i + 1];
        sz[i] = verts[3 * i + 2];
    }
    __syncthreads();

    const int r = blockIdx.x * 64 + tid;
    if (r >= R) return;

    const int4* t4 = (const int4*)tetras;
    short* myseq = seq + (size_t)r * S_MAX;

    const double tmin = tmin_in[r];
    const bool   hit  = tmin < 5.0;
    const double t0   = hit ? tmin : 0.0;
    out_tstart[r] = (float)t0;
    out_tend[r]   = hit ? (float)(t0 + 0.05) : 0.0f;

    if (!hit) {
        for (int k = 0; k < S_MAX; ++k) myseq[k] = -1;
        return;
    }

    const double ox = (double)ro[3 * r + 0], oy = (double)ro[3 * r + 1], oz = (double)ro[3 * r + 2];
    const double dx = (double)rd[3 * r + 0], dy = (double)rd[3 * r + 1], dz = (double)rd[3 * r + 2];
    const double hpx = ox + t0 * dx, hpy = oy + t0 * dy, hpz = oz + t0 * dz;

    int  tet   = fidx_in[r] >> 2;
    bool alive = true;

    double v0x, v0y, v0z, inv[9];
    build_inv(tet, t4, sx, sy, sz, v0x, v0y, v0z, inv);

    // affine coefficients: w_i(toff) = wb_i + toff * wd_i
    double wb1, wb2, wb3, wb0, wd1, wd2, wd3, wd0;
    {
        const double bx = hpx - v0x, by = hpy - v0y, bz = hpz - v0z;
        wb1 = inv[0] * bx + inv[1] * by + inv[2] * bz;
        wb2 = inv[3] * bx + inv[4] * by + inv[5] * bz;
        wb3 = inv[6] * bx + inv[7] * by + inv[8] * bz;
        wd1 = inv[0] * dx + inv[1] * dy + inv[2] * dz;
        wd2 = inv[3] * dx + inv[4] * dy + inv[5] * dz;
        wd3 = inv[6] * dx + inv[7] * dy + inv[8] * dz;
        wb0 = 1.0 - (wb1 + wb2 + wb3);
        wd0 = -(wd1 + wd2 + wd3);
    }

    for (int k = 0; k < S_MAX; ++k) {
        if (!alive) { myseq[k] = -1; continue; }

        const double toff = (double)k * STEPD + 1e-4;
        {
            const double a0 = wb0 + toff * wd0;
            const double a1 = wb1 + toff * wd1;
            const double a2 = wb2 + toff * wd2;
            const double a3 = wb3 + toff * wd3;
            const bool ins = (a0 >= -1e-6) && (a1 >= -1e-6) && (a2 >= -1e-6) && (a3 >= -1e-6);
            const bool near = (fabs(a0 + 1e-6) < 1e-12) || (fabs(a1 + 1e-6) < 1e-12) ||
                              (fabs(a2 + 1e-6) < 1e-12) || (fabs(a3 + 1e-6) < 1e-12);
            if (ins && !near) { myseq[k] = (short)tet; continue; }
        }

        // exact path: round-4-identical matvec + walk
        const double px = hpx + toff * dx;
        const double py = hpy + toff * dy;
        const double pz = hpz + toff * dz;

        double b1 = px - v0x, b2 = py - v0y, b3 = pz - v0z;
        double w1 = inv[0] * b1 + inv[1] * b2 + inv[2] * b3;
        double w2 = inv[3] * b1 + inv[4] * b2 + inv[5] * b3;
        double w3 = inv[6] * b1 + inv[7] * b2 + inv[8] * b3;
        double w0 = 1.0 - (w1 + w2 + w3);
        bool inside = (w0 >= -1e-6) && (w1 >= -1e-6) && (w2 >= -1e-6) && (w3 >= -1e-6);

        int it = 0;
        bool moved = false;
        while (!inside && it < 3) {
            int    jm = 0;
            double wb = w0;
            if (w1 < wb) { wb = w1; jm = 1; }
            if (w2 < wb) { wb = w2; jm = 2; }
            if (w3 < wb) { wb = w3; jm = 3; }
            const int nb = topo[tet * 4 + (3 - jm)];
            if (nb < 0) { alive = false; break; }
            tet = nb;
            moved = true;
            build_inv(tet, t4, sx, sy, sz, v0x, v0y, v0z, inv);
            b1 = px - v0x; b2 = py - v0y; b3 = pz - v0z;
            w1 = inv[0] * b1 + inv[1] * b2 + inv[2] * b3;
            w2 = inv[3] * b1 + inv[4] * b2 + inv[5] * b3;
            w3 = inv[6] * b1 + inv[7] * b2 + inv[8] * b3;
            w0 = 1.0 - (w1 + w2 + w3);
            inside = (w0 >= -1e-6) && (w1 >= -1e-6) && (w2 >= -1e-6) && (w3 >= -1e-6);
            ++it;
        }

        if (moved) {
            const double bx = hpx - v0x, by = hpy - v0y, bz = hpz - v0z;
            wb1 = inv[0] * bx + inv[1] * by + inv[2] * bz;
            wb2 = inv[3] * bx + inv[4] * by + inv[5] * bz;
            wb3 = inv[6] * bx + inv[7] * by + inv[8] * bz;
            wd1 = inv[0] * dx + inv[1] * dy + inv[2] * dz;
            wd2 = inv[3] * dx + inv[4] * dy + inv[5] * dz;
            wd3 = inv[6] * dx + inv[7] * dy + inv[8] * dz;
            wb0 = 1.0 - (wb1 + wb2 + wb3);
            wd0 = -(wd1 + wd2 + wd3);
        }

        myseq[k] = (alive && inside) ? (short)tet : (short)-1;
    }
}

// ---------------------------------------------------------------------------
// Kernel 3 (parallel emission): thread = (ray, sample). Coalesced writes.
// ---------------------------------------------------------------------------
__global__ __launch_bounds__(256) void emit_kernel(
    const float* __restrict__ verts,
    const float* __restrict__ ro,
    const float* __restrict__ rd,
    const int*   __restrict__ tetras,
    const double* __restrict__ tmin_in,
    const short*  __restrict__ seq,
    float* __restrict__ out_rayidx,
    float* __restrict__ out_tetidx,
    float* __restrict__ out_bary,
    float* __restrict__ out_pos,
    int NV, int R)
{
    __shared__ float sx[NV_MAX], sy[NV_MAX], sz[NV_MAX];
    const int tid = threadIdx.x;
    for (int i = tid; i < NV; i += 256) {
        sx[i] = verts[3 * i + 0];
        sy[i] = verts[3 * i + 1];
        sz[i] = verts[3 * i + 2];
    }
    __syncthreads();

    const int idx = blockIdx.x * 256 + tid;
    if (idx >= R * S_MAX) return;
    const int r = idx >> 7;
    const int k = idx & (S_MAX - 1);

    const int tk = (int)seq[idx];
    if (tk < 0) {
        out_rayidx[idx] = -1.0f;
        out_tetidx[idx] = -1.0f;
        ((float4*)out_bary)[idx] = make_float4(0.0f, 0.0f, 0.0f, 0.0f);
        out_pos[idx * 3 + 0] = 0.0f;
        out_pos[idx * 3 + 1] = 0.0f;
        out_pos[idx * 3 + 2] = 0.0f;
        return;
    }

    const double tmin = tmin_in[r];
    const double t0   = (tmin < 5.0) ? tmin : 0.0;
    const double ox = (double)ro[3 * r + 0], oy = (double)ro[3 * r + 1], oz = (double)ro[3 * r + 2];
    const double dx = (double)rd[3 * r + 0], dy = (double)rd[3 * r + 1], dz = (double)rd[3 * r + 2];
    const double toff = (double)k * STEPD + 1e-4;
    const double px = (ox + t0 * dx) + toff * dx;
    const double py = (oy + t0 * dy) + toff * dy;
    const double pz = (oz + t0 * dz) + toff * dz;

    double v0x, v0y, v0z, inv[9];
    build_inv(tk, (const int4*)tetras, sx, sy, sz, v0x, v0y, v0z, inv);
    const double b1 = px - v0x, b2 = py - v0y, b3 = pz - v0z;
    const double w1 = inv[0] * b1 + inv[1] * b2 + inv[2] * b3;
    const double w2 = inv[3] * b1 + inv[4] * b2 + inv[5] * b3;
    const double w3 = inv[6] * b1 + inv[7] * b2 + inv[8] * b3;
    const double w0 = 1.0 - (w1 + w2 + w3);

    out_rayidx[idx] = (float)r;
    out_tetidx[idx] = (float)tk;
    ((float4*)out_bary)[idx] = make_float4((float)w0, (float)w1, (float)w2, (float)w3);
    out_pos[idx * 3 + 0] = (float)px;
    out_pos[idx * 3 + 1] = (float)py;
    out_pos[idx * 3 + 2] = (float)pz;
}

extern "C" void kernel_launch(void* const* d_in, const int* in_sizes, int n_in,
                              void* d_out, int out_size, void* d_ws, size_t ws_size,
                              hipStream_t stream) {
    const float* verts  = (const float*)d_in[0];
    const float* ro     = (const float*)d_in[1];
    const float* rd     = (const float*)d_in[2];
    const int*   tetras = (const int*)d_in[3];
    const int*   faces  = (const int*)d_in[4];
    const int*   topo   = (const int*)d_in[5];

    const int NV = in_sizes[0] / 3;
    const int R  = in_sizes[1] / 3;
    const int NF = in_sizes[4] / 3;
    const int S  = S_MAX;

    // workspace: tmin f64[R] | fidx i32[R] | seq i16[R*S]
    double* wtmin = (double*)d_ws;
    int*    wfidx = (int*)(wtmin + R);
    short*  wseq  = (short*)(wfidx + R);

    float* out        = (float*)d_out;
    float* out_rayidx = out;
    float* out_tetidx = out + (size_t)R * S;
    float* out_bary   = out + (size_t)2 * R * S;
    float* out_tstart = out + (size_t)6 * R * S;
    float* out_tend   = out_tstart + R;
    float* out_pos    = out_tend + R;

    isect_kernel<<<(R + 3) / 4, 256, 0, stream>>>(verts, ro, rd, faces, wtmin, wfidx, NV, NF, R);
    walk_kernel<<<(R + 63) / 64, 64, 0, stream>>>(verts, ro, rd, tetras, topo, wtmin, wfidx,
                                                  wseq, out_tstart, out_tend, NV, R);
    emit_kernel<<<(R * S + 255) / 256, 256, 0, stream>>>(verts, ro, rd, tetras, wtmin, wseq,
                                                         out_rayidx, out_tetidx, out_bary, out_pos,
                                                         NV, R);
}

// Round 6
// 142.433 us; speedup vs baseline: 2.1036x; 1.0311x over previous
//
#include <hip/hip_runtime.h>

#define S_MAX 128
#define NV_MAX 729
#define STEPD (0.05 / 128.0)
#define GUARD 1e-12

// ---------------------------------------------------------------------------
// Exact f64 Moller-Trumbore for face F (round-3-identical). Returns t or 1e10.
// ---------------------------------------------------------------------------
static __device__ __forceinline__ double mt_eval_f64(
    int F, const int* __restrict__ faces,
    const float* sx, const float* sy, const float* sz,
    double ox, double oy, double oz,
    double dx, double dy, double dz)
{
    const int i0 = faces[3 * F + 0];
    const int i1 = faces[3 * F + 1];
    const int i2 = faces[3 * F + 2];
    const double p0x = (double)sx[i0], p0y = (double)sy[i0], p0z = (double)sz[i0];
    const double e1x = (double)sx[i1] - p0x, e1y = (double)sy[i1] - p0y, e1z = (double)sz[i1] - p0z;
    const double e2x = (double)sx[i2] - p0x, e2y = (double)sy[i2] - p0y, e2z = (double)sz[i2] - p0z;
    const double hx = dy * e2z - dz * e2y;
    const double hy = dz * e2x - dx * e2z;
    const double hz = dx * e2y - dy * e2x;
    const double a  = e1x * hx + e1y * hy + e1z * hz;
    const bool oka = fabs(a) > 1e-9;
    const double f  = 1.0 / (oka ? a : 1e-9);
    const double s0 = ox - p0x, s1 = oy - p0y, s2 = oz - p0z;
    const double u  = f * (s0 * hx + s1 * hy + s2 * hz);
    const double qx = s1 * e1z - s2 * e1y;
    const double qy = s2 * e1x - s0 * e1z;
    const double qz = s0 * e1y - s1 * e1x;
    const double v  = f * (dx * qx + dy * qy + dz * qz);
    double t        = f * (e2x * qx + e2y * qy + e2z * qz);
    const bool ok = oka && (u >= 0.0) && (u <= 1.0) && (v >= 0.0) &&
                    (u + v <= 1.0) && (t > 1e-6);
    return ok ? t : 1e10;
}

// ---------------------------------------------------------------------------
// Kernel 0: precompute per-tet {v0, inv(M)} in f64 (build_inv-identical
// expressions) + mesh bounds (layer-0 z range, xy jitter margin).
// winv layout: 12 doubles per tet: v0x,v0y,v0z, inv[0..8] (row-major).
// ---------------------------------------------------------------------------
__global__ __launch_bounds__(256) void prep_kernel(
    const float* __restrict__ verts,
    const int*   __restrict__ tetras,
    double* __restrict__ winv,
    float*  __restrict__ wbnd,     // [4]: zmin0, zmax0, marg, pad
    int NV, int NT)
{
    const int tid = threadIdx.x;
    const int t = blockIdx.x * 256 + tid;
    if (t < NT) {
        const int4 tv = ((const int4*)tetras)[t];
        const double v0x = (double)verts[3 * tv.x + 0];
        const double v0y = (double)verts[3 * tv.x + 1];
        const double v0z = (double)verts[3 * tv.x + 2];
        const double m11 = (double)verts[3 * tv.y + 0] - v0x, m21 = (double)verts[3 * tv.y + 1] - v0y, m31 = (double)verts[3 * tv.y + 2] - v0z;
        const double m12 = (double)verts[3 * tv.z + 0] - v0x, m22 = (double)verts[3 * tv.z + 1] - v0y, m32 = (double)verts[3 * tv.z + 2] - v0z;
        const double m13 = (double)verts[3 * tv.w + 0] - v0x, m23 = (double)verts[3 * tv.w + 1] - v0y, m33 = (double)verts[3 * tv.w + 2] - v0z;
        const double A = m22 * m33 - m23 * m32;
        const double B = m21 * m33 - m23 * m31;
        const double C = m21 * m32 - m22 * m31;
        const double det = m11 * A - m12 * B + m13 * C;
        const double rcp = 1.0 / det;
        double* o = winv + 12 * (size_t)t;
        o[0] = v0x; o[1] = v0y; o[2] = v0z;
        o[3]  = A * rcp;  o[4]  = (m13 * m32 - m12 * m33) * rcp;  o[5]  = (m12 * m23 - m13 * m22) * rcp;
        o[6]  = -B * rcp; o[7]  = (m11 * m33 - m13 * m31) * rcp;  o[8]  = (m13 * m21 - m11 * m23) * rcp;
        o[9]  = C * rcp;  o[10] = (m12 * m31 - m11 * m32) * rcp;  o[11] = (m11 * m22 - m12 * m21) * rcp;
    }
    if (blockIdx.x == 0) {
        __shared__ float red[256];
        float zmin = 1e9f, zmax = -1e9f, dev = 0.0f;
        for (int i = tid; i < NV; i += 256) {
            const float x = verts[3 * i + 0], y = verts[3 * i + 1], z = verts[3 * i + 2];
            if (i % 9 == 0) { zmin = fminf(zmin, z); zmax = fmaxf(zmax, z); }
            dev = fmaxf(dev, fabsf(x - rintf(x * 8.0f) * 0.125f));
            dev = fmaxf(dev, fabsf(y - rintf(y * 8.0f) * 0.125f));
        }
        red[tid] = zmin; __syncthreads();
        for (int s = 128; s; s >>= 1) { if (tid < s) red[tid] = fminf(red[tid], red[tid + s]); __syncthreads(); }
        if (tid == 0) wbnd[0] = red[0];
        __syncthreads();
        red[tid] = zmax; __syncthreads();
        for (int s = 128; s; s >>= 1) { if (tid < s) red[tid] = fmaxf(red[tid], red[tid + s]); __syncthreads(); }
        if (tid == 0) wbnd[1] = red[0];
        __syncthreads();
        red[tid] = dev; __syncthreads();
        for (int s = 128; s; s >>= 1) { if (tid < s) red[tid] = fmaxf(red[tid], red[tid + s]); __syncthreads(); }
        if (tid == 0) wbnd[2] = red[0] + 1e-5f;
    }
}

// ---------------------------------------------------------------------------
// Kernel 1: first hit. One wave per ray; candidate set = 24 faces per layer-0
// cell overlapping the ray's xy-track (sound cover; full-scan fallback).
// ---------------------------------------------------------------------------
__global__ __launch_bounds__(256) void isect_kernel(
    const float* __restrict__ verts,
    const float* __restrict__ ro,
    const float* __restrict__ rd,
    const int*   __restrict__ faces,
    const float* __restrict__ wbnd,
    double* __restrict__ tmin_out,
    int*    __restrict__ fidx_out,
    int NV, int NF, int R)
{
    __shared__ float sx[NV_MAX], sy[NV_MAX], sz[NV_MAX];
    const int tid = threadIdx.x;
    for (int i = tid; i < NV; i += 256) {
        sx[i] = verts[3 * i + 0];
        sy[i] = verts[3 * i + 1];
        sz[i] = verts[3 * i + 2];
    }
    __syncthreads();

    const float s_zmin = wbnd[0], s_zmax = wbnd[1], s_marg = wbnd[2];

    const int wv = tid >> 6, lane = tid & 63;
    const int r = blockIdx.x * 4 + wv;
    if (r >= R) return;

    const double ox = (double)ro[3 * r + 0], oy = (double)ro[3 * r + 1], oz = (double)ro[3 * r + 2];
    const double dx = (double)rd[3 * r + 0], dy = (double)rd[3 * r + 1], dz = (double)rd[3 * r + 2];

    int ncand = 0, ixlo = 0, iylo = 0, ny = 1;
    if (dz > 0.0) {
        const double t_lo = ((double)s_zmin - oz) / dz;
        const double t_hi = ((double)s_zmax - oz) / dz;
        const double marg = (double)s_marg + 1e-9;
        const double xa = ox + t_lo * dx, xb = ox + t_hi * dx;
        const double ya = oy + t_lo * dy, yb = oy + t_hi * dy;
        const double xlo = fmin(xa, xb) - marg, xhi = fmax(xa, xb) + marg;
        const double ylo = fmin(ya, yb) - marg, yhi = fmax(ya, yb) + marg;
        const int ix0 = max(0, (int)floor(xlo * 8.0)), ix1 = min(7, (int)floor(xhi * 8.0));
        const int iy0 = max(0, (int)floor(ylo * 8.0)), iy1 = min(7, (int)floor(yhi * 8.0));
        if (ix0 <= ix1 && iy0 <= iy1) {
            ixlo = ix0; iylo = iy0;
            ny = iy1 - iy0 + 1;
            ncand = (ix1 - ix0 + 1) * ny * 24;
        }
    }

    double bt = 1e10;
    int    bi = 0x7fffffff;
    for (int c = lane; c < ncand; c += 64) {
        const int cell = c / 24, fk = c - cell * 24;
        const int cx = cell / ny, cy = cell - cx * ny;
        const int F = ((ixlo + cx) * 64 + (iylo + cy) * 8) * 24 + fk;
        const double t = mt_eval_f64(F, faces, sx, sy, sz, ox, oy, oz, dx, dy, dz);
        if (t < bt || (t == bt && F < bi)) { bt = t; bi = F; }
    }
    for (int off = 32; off; off >>= 1) {
        const double t2 = __shfl_down(bt, off);
        const int    i2 = __shfl_down(bi, off);
        if (t2 < bt || (t2 == bt && i2 < bi)) { bt = t2; bi = i2; }
    }
    const double btw = __shfl(bt, 0);
    if (btw >= 1e10) {                       // fallback: full scan (≈never)
        bt = 1e10; bi = 0x7fffffff;
        for (int F = lane; F < NF; F += 64) {
            const double t = mt_eval_f64(F, faces, sx, sy, sz, ox, oy, oz, dx, dy, dz);
            if (t < bt || (t == bt && F < bi)) { bt = t; bi = F; }
        }
        for (int off = 32; off; off >>= 1) {
            const double t2 = __shfl_down(bt, off);
            const int    i2 = __shfl_down(bi, off);
            if (t2 < bt || (t2 == bt && i2 < bi)) { bt = t2; bi = i2; }
        }
    }
    if (lane == 0) { tmin_out[r] = bt; fidx_out[r] = bi; }
}

// ---------------------------------------------------------------------------
// Kernel 2: event-driven per-ray walk. Per-lane state machine: tight affine
// fast-scan (no long-latency ops) between exact events (matvec from
// precomputed inv + <=3 moves). Numerics identical to round 5.
// ---------------------------------------------------------------------------
__global__ __launch_bounds__(64) void walk_kernel(
    const float* __restrict__ ro,
    const float* __restrict__ rd,
    const int*   __restrict__ topo,
    const double* __restrict__ tmin_in,
    const int*    __restrict__ fidx_in,
    const double* __restrict__ winv,
    short* __restrict__ seq,
    float* __restrict__ out_tstart,
    float* __restrict__ out_tend,
    int R)
{
    const int r = blockIdx.x * 64 + threadIdx.x;
    if (r >= R) return;

    short* myseq = seq + (size_t)r * S_MAX;

    const double tmin = tmin_in[r];
    const bool   hit  = tmin < 5.0;
    const double t0   = hit ? tmin : 0.0;
    out_tstart[r] = (float)t0;
    out_tend[r]   = hit ? (float)(t0 + 0.05) : 0.0f;
    if (!hit) {
        for (int k = 0; k < S_MAX; ++k) myseq[k] = -1;
        return;
    }

    const double ox = (double)ro[3 * r + 0], oy = (double)ro[3 * r + 1], oz = (double)ro[3 * r + 2];
    const double dx = (double)rd[3 * r + 0], dy = (double)rd[3 * r + 1], dz = (double)rd[3 * r + 2];
    const double hpx = ox + t0 * dx, hpy = oy + t0 * dy, hpz = oz + t0 * dz;

    int  tet   = fidx_in[r] >> 2;
    bool alive = true;

    const double* rec = winv + 12 * (size_t)tet;
    double v0x = rec[0], v0y = rec[1], v0z = rec[2];
    double i0 = rec[3], i1 = rec[4],  i2 = rec[5];
    double i3 = rec[6], i4 = rec[7],  i5 = rec[8];
    double i6 = rec[9], i7 = rec[10], i8 = rec[11];

    double wb0, wb1, wb2, wb3, wd0, wd1, wd2, wd3;
    {
        const double bx = hpx - v0x, by = hpy - v0y, bz = hpz - v0z;
        wb1 = i0 * bx + i1 * by + i2 * bz;
        wb2 = i3 * bx + i4 * by + i5 * bz;
        wb3 = i6 * bx + i7 * by + i8 * bz;
        wd1 = i0 * dx + i1 * dy + i2 * dz;
        wd2 = i3 * dx + i4 * dy + i5 * dz;
        wd3 = i6 * dx + i7 * dy + i8 * dz;
        wb0 = 1.0 - (wb1 + wb2 + wb3);
        wd0 = -(wd1 + wd2 + wd3);
    }

    int k = 0;
    while (k < S_MAX) {
        // ---- fast scan: affine inside with margin >= GUARD ----
        while (k < S_MAX) {
            const double toff = (double)k * STEPD + 1e-4;
            const double a0 = wb0 + toff * wd0;
            const double a1 = wb1 + toff * wd1;
            const double a2 = wb2 + toff * wd2;
            const double a3 = wb3 + toff * wd3;
            const double mn = fmin(fmin(a0, a1), fmin(a2, a3));
            if (mn + 1e-6 >= GUARD) { myseq[k] = (short)tet; ++k; }
            else break;
        }
        if (k >= S_MAX) break;

        // ---- exact event at sample k (round-4/5-identical decision path) ----
        const double toff = (double)k * STEPD + 1e-4;
        const double px = hpx + toff * dx;
        const double py = hpy + toff * dy;
        const double pz = hpz + toff * dz;

        double b1 = px - v0x, b2 = py - v0y, b3 = pz - v0z;
        double w1 = i0 * b1 + i1 * b2 + i2 * b3;
        double w2 = i3 * b1 + i4 * b2 + i5 * b3;
        double w3 = i6 * b1 + i7 * b2 + i8 * b3;
        double w0 = 1.0 - (w1 + w2 + w3);
        bool inside = (w0 >= -1e-6) && (w1 >= -1e-6) && (w2 >= -1e-6) && (w3 >= -1e-6);

        int it = 0;
        bool moved = false;
        while (!inside && it < 3) {
            int    jm = 0;
            double wb = w0;
            if (w1 < wb) { wb = w1; jm = 1; }
            if (w2 < wb) { wb = w2; jm = 2; }
            if (w3 < wb) { wb = w3; jm = 3; }
            const int nb = topo[tet * 4 + (3 - jm)];
            if (nb < 0) { alive = false; break; }
            tet = nb;
            moved = true;
            rec = winv + 12 * (size_t)tet;
            v0x = rec[0]; v0y = rec[1]; v0z = rec[2];
            i0 = rec[3]; i1 = rec[4];  i2 = rec[5];
            i3 = rec[6]; i4 = rec[7];  i5 = rec[8];
            i6 = rec[9]; i7 = rec[10]; i8 = rec[11];
            b1 = px - v0x; b2 = py - v0y; b3 = pz - v0z;
            w1 = i0 * b1 + i1 * b2 + i2 * b3;
            w2 = i3 * b1 + i4 * b2 + i5 * b3;
            w3 = i6 * b1 + i7 * b2 + i8 * b3;
            w0 = 1.0 - (w1 + w2 + w3);
            inside = (w0 >= -1e-6) && (w1 >= -1e-6) && (w2 >= -1e-6) && (w3 >= -1e-6);
            ++it;
        }
        if (!alive) break;

        myseq[k] = inside ? (short)tet : (short)-1;
        ++k;

        if (moved) {
            const double bx = hpx - v0x, by = hpy - v0y, bz = hpz - v0z;
            wb1 = i0 * bx + i1 * by + i2 * bz;
            wb2 = i3 * bx + i4 * by + i5 * bz;
            wb3 = i6 * bx + i7 * by + i8 * bz;
            wd1 = i0 * dx + i1 * dy + i2 * dz;
            wd2 = i3 * dx + i4 * dy + i5 * dz;
            wd3 = i6 * dx + i7 * dy + i8 * dz;
            wb0 = 1.0 - (wb1 + wb2 + wb3);
            wd0 = -(wd1 + wd2 + wd3);
        }
    }
    for (; k < S_MAX; ++k) myseq[k] = -1;
}

// ---------------------------------------------------------------------------
// Kernel 3: parallel emission, coalesced writes, precomputed inv.
// ---------------------------------------------------------------------------
__global__ __launch_bounds__(256) void emit_kernel(
    const float* __restrict__ ro,
    const float* __restrict__ rd,
    const double* __restrict__ tmin_in,
    const short*  __restrict__ seq,
    const double* __restrict__ winv,
    float* __restrict__ out_rayidx,
    float* __restrict__ out_tetidx,
    float* __restrict__ out_bary,
    float* __restrict__ out_pos,
    int R)
{
    const int idx = blockIdx.x * 256 + threadIdx.x;
    if (idx >= R * S_MAX) return;
    const int r = idx >> 7;
    const int k = idx & (S_MAX - 1);

    const int tk = (int)seq[idx];
    if (tk < 0) {
        out_rayidx[idx] = -1.0f;
        out_tetidx[idx] = -1.0f;
        ((float4*)out_bary)[idx] = make_float4(0.0f, 0.0f, 0.0f, 0.0f);
        out_pos[idx * 3 + 0] = 0.0f;
        out_pos[idx * 3 + 1] = 0.0f;
        out_pos[idx * 3 + 2] = 0.0f;
        return;
    }

    const double tmin = tmin_in[r];
    const double t0   = (tmin < 5.0) ? tmin : 0.0;
    const double ox = (double)ro[3 * r + 0], oy = (double)ro[3 * r + 1], oz = (double)ro[3 * r + 2];
    const double dx = (double)rd[3 * r + 0], dy = (double)rd[3 * r + 1], dz = (double)rd[3 * r + 2];
    const double toff = (double)k * STEPD + 1e-4;
    const double px = (ox + t0 * dx) + toff * dx;
    const double py = (oy + t0 * dy) + toff * dy;
    const double pz = (oz + t0 * dz) + toff * dz;

    const double* rec = winv + 12 * (size_t)tk;
    const double b1 = px - rec[0], b2 = py - rec[1], b3 = pz - rec[2];
    const double w1 = rec[3] * b1 + rec[4]  * b2 + rec[5]  * b3;
    const double w2 = rec[6] * b1 + rec[7]  * b2 + rec[8]  * b3;
    const double w3 = rec[9] * b1 + rec[10] * b2 + rec[11] * b3;
    const double w0 = 1.0 - (w1 + w2 + w3);

    out_rayidx[idx] = (float)r;
    out_tetidx[idx] = (float)tk;
    ((float4*)out_bary)[idx] = make_float4((float)w0, (float)w1, (float)w2, (float)w3);
    out_pos[idx * 3 + 0] = (float)px;
    out_pos[idx * 3 + 1] = (float)py;
    out_pos[idx * 3 + 2] = (float)pz;
}

extern "C" void kernel_launch(void* const* d_in, const int* in_sizes, int n_in,
                              void* d_out, int out_size, void* d_ws, size_t ws_size,
                              hipStream_t stream) {
    const float* verts  = (const float*)d_in[0];
    const float* ro     = (const float*)d_in[1];
    const float* rd     = (const float*)d_in[2];
    const int*   tetras = (const int*)d_in[3];
    const int*   faces  = (const int*)d_in[4];
    const int*   topo   = (const int*)d_in[5];

    const int NV = in_sizes[0] / 3;
    const int R  = in_sizes[1] / 3;
    const int NT = in_sizes[3] / 4;
    const int NF = in_sizes[4] / 3;
    const int S  = S_MAX;

    // ws layout (8B-aligned first): tmin f64[R] | inv f64[12*NT] | bnd f32[4] | fidx i32[R] | seq i16[R*S]
    double* wtmin = (double*)d_ws;
    double* winv  = wtmin + R;
    float*  wbnd  = (float*)(winv + 12 * (size_t)NT);
    int*    wfidx = (int*)(wbnd + 4);
    short*  wseq  = (short*)(wfidx + R);

    float* out        = (float*)d_out;
    float* out_rayidx = out;
    float* out_tetidx = out + (size_t)R * S;
    float* out_bary   = out + (size_t)2 * R * S;
    float* out_tstart = out + (size_t)6 * R * S;
    float* out_tend   = out_tstart + R;
    float* out_pos    = out_tend + R;

    prep_kernel<<<(NT + 255) / 256, 256, 0, stream>>>(verts, tetras, winv, wbnd, NV, NT);
    isect_kernel<<<(R + 3) / 4, 256, 0, stream>>>(verts, ro, rd, faces, wbnd, wtmin, wfidx, NV, NF, R);
    walk_kernel<<<(R + 63) / 64, 64, 0, stream>>>(ro, rd, topo, wtmin, wfidx, winv,
                                                  wseq, out_tstart, out_tend, R);
    emit_kernel<<<(R * S + 255) / 256, 256, 0, stream>>>(ro, rd, wtmin, wseq, winv,
                                                         out_rayidx, out_tetidx, out_bary, out_pos, R);
}

// Round 7
// 99.024 us; speedup vs baseline: 3.0257x; 1.4384x over previous
//
#include <hip/hip_runtime.h>

#define S_MAX 128
#define NV_MAX 729
#define STEPD (0.05 / 128.0)
#define GUARD 1e-12

// ---------------------------------------------------------------------------
// Exact f64 Moller-Trumbore for face F (round-3-identical). Returns t or 1e10.
// ---------------------------------------------------------------------------
static __device__ __forceinline__ double mt_eval_f64(
    int F, const int* __restrict__ faces,
    const float* sx, const float* sy, const float* sz,
    double ox, double oy, double oz,
    double dx, double dy, double dz)
{
    const int i0 = faces[3 * F + 0];
    const int i1 = faces[3 * F + 1];
    const int i2 = faces[3 * F + 2];
    const double p0x = (double)sx[i0], p0y = (double)sy[i0], p0z = (double)sz[i0];
    const double e1x = (double)sx[i1] - p0x, e1y = (double)sy[i1] - p0y, e1z = (double)sz[i1] - p0z;
    const double e2x = (double)sx[i2] - p0x, e2y = (double)sy[i2] - p0y, e2z = (double)sz[i2] - p0z;
    const double hx = dy * e2z - dz * e2y;
    const double hy = dz * e2x - dx * e2z;
    const double hz = dx * e2y - dy * e2x;
    const double a  = e1x * hx + e1y * hy + e1z * hz;
    const bool oka = fabs(a) > 1e-9;
    const double f  = 1.0 / (oka ? a : 1e-9);
    const double s0 = ox - p0x, s1 = oy - p0y, s2 = oz - p0z;
    const double u  = f * (s0 * hx + s1 * hy + s2 * hz);
    const double qx = s1 * e1z - s2 * e1y;
    const double qy = s2 * e1x - s0 * e1z;
    const double qz = s0 * e1y - s1 * e1x;
    const double v  = f * (dx * qx + dy * qy + dz * qz);
    double t        = f * (e2x * qx + e2y * qy + e2z * qz);
    const bool ok = oka && (u >= 0.0) && (u <= 1.0) && (v >= 0.0) &&
                    (u + v <= 1.0) && (t > 1e-6);
    return ok ? t : 1e10;
}

// ---------------------------------------------------------------------------
// Kernel 0: precompute per-tet {v0, inv(M)} in f64 + mesh bounds.
// winv layout: 12 doubles per tet: v0x,v0y,v0z, inv[0..8] (row-major).
// ---------------------------------------------------------------------------
__global__ __launch_bounds__(256) void prep_kernel(
    const float* __restrict__ verts,
    const int*   __restrict__ tetras,
    double* __restrict__ winv,
    float*  __restrict__ wbnd,     // [4]: zmin0, zmax0, marg, pad
    int NV, int NT)
{
    const int tid = threadIdx.x;
    const int t = blockIdx.x * 256 + tid;
    if (t < NT) {
        const int4 tv = ((const int4*)tetras)[t];
        const double v0x = (double)verts[3 * tv.x + 0];
        const double v0y = (double)verts[3 * tv.x + 1];
        const double v0z = (double)verts[3 * tv.x + 2];
        const double m11 = (double)verts[3 * tv.y + 0] - v0x, m21 = (double)verts[3 * tv.y + 1] - v0y, m31 = (double)verts[3 * tv.y + 2] - v0z;
        const double m12 = (double)verts[3 * tv.z + 0] - v0x, m22 = (double)verts[3 * tv.z + 1] - v0y, m32 = (double)verts[3 * tv.z + 2] - v0z;
        const double m13 = (double)verts[3 * tv.w + 0] - v0x, m23 = (double)verts[3 * tv.w + 1] - v0y, m33 = (double)verts[3 * tv.w + 2] - v0z;
        const double A = m22 * m33 - m23 * m32;
        const double B = m21 * m33 - m23 * m31;
        const double C = m21 * m32 - m22 * m31;
        const double det = m11 * A - m12 * B + m13 * C;
        const double rcp = 1.0 / det;
        double* o = winv + 12 * (size_t)t;
        o[0] = v0x; o[1] = v0y; o[2] = v0z;
        o[3]  = A * rcp;  o[4]  = (m13 * m32 - m12 * m33) * rcp;  o[5]  = (m12 * m23 - m13 * m22) * rcp;
        o[6]  = -B * rcp; o[7]  = (m11 * m33 - m13 * m31) * rcp;  o[8]  = (m13 * m21 - m11 * m23) * rcp;
        o[9]  = C * rcp;  o[10] = (m12 * m31 - m11 * m32) * rcp;  o[11] = (m11 * m22 - m12 * m21) * rcp;
    }
    if (blockIdx.x == 0) {
        __shared__ float red[256];
        float zmin = 1e9f, zmax = -1e9f, dev = 0.0f;
        for (int i = tid; i < NV; i += 256) {
            const float x = verts[3 * i + 0], y = verts[3 * i + 1], z = verts[3 * i + 2];
            if (i % 9 == 0) { zmin = fminf(zmin, z); zmax = fmaxf(zmax, z); }
            dev = fmaxf(dev, fabsf(x - rintf(x * 8.0f) * 0.125f));
            dev = fmaxf(dev, fabsf(y - rintf(y * 8.0f) * 0.125f));
        }
        red[tid] = zmin; __syncthreads();
        for (int s = 128; s; s >>= 1) { if (tid < s) red[tid] = fminf(red[tid], red[tid + s]); __syncthreads(); }
        if (tid == 0) wbnd[0] = red[0];
        __syncthreads();
        red[tid] = zmax; __syncthreads();
        for (int s = 128; s; s >>= 1) { if (tid < s) red[tid] = fmaxf(red[tid], red[tid + s]); __syncthreads(); }
        if (tid == 0) wbnd[1] = red[0];
        __syncthreads();
        red[tid] = dev; __syncthreads();
        for (int s = 128; s; s >>= 1) { if (tid < s) red[tid] = fmaxf(red[tid], red[tid + s]); __syncthreads(); }
        if (tid == 0) wbnd[2] = red[0] + 1e-5f;
    }
}

// ---------------------------------------------------------------------------
// Kernel 1: first hit. One wave per ray; candidate set = 24 faces per layer-0
// cell overlapping the ray's xy-track (sound cover; full-scan fallback).
// ---------------------------------------------------------------------------
__global__ __launch_bounds__(256) void isect_kernel(
    const float* __restrict__ verts,
    const float* __restrict__ ro,
    const float* __restrict__ rd,
    const int*   __restrict__ faces,
    const float* __restrict__ wbnd,
    double* __restrict__ tmin_out,
    int*    __restrict__ fidx_out,
    int NV, int NF, int R)
{
    __shared__ float sx[NV_MAX], sy[NV_MAX], sz[NV_MAX];
    const int tid = threadIdx.x;
    for (int i = tid; i < NV; i += 256) {
        sx[i] = verts[3 * i + 0];
        sy[i] = verts[3 * i + 1];
        sz[i] = verts[3 * i + 2];
    }
    __syncthreads();

    const float s_zmin = wbnd[0], s_zmax = wbnd[1], s_marg = wbnd[2];

    const int wv = tid >> 6, lane = tid & 63;
    const int r = blockIdx.x * 4 + wv;
    if (r >= R) return;

    const double ox = (double)ro[3 * r + 0], oy = (double)ro[3 * r + 1], oz = (double)ro[3 * r + 2];
    const double dx = (double)rd[3 * r + 0], dy = (double)rd[3 * r + 1], dz = (double)rd[3 * r + 2];

    int ncand = 0, ixlo = 0, iylo = 0, ny = 1;
    if (dz > 0.0) {
        const double t_lo = ((double)s_zmin - oz) / dz;
        const double t_hi = ((double)s_zmax - oz) / dz;
        const double marg = (double)s_marg + 1e-9;
        const double xa = ox + t_lo * dx, xb = ox + t_hi * dx;
        const double ya = oy + t_lo * dy, yb = oy + t_hi * dy;
        const double xlo = fmin(xa, xb) - marg, xhi = fmax(xa, xb) + marg;
        const double ylo = fmin(ya, yb) - marg, yhi = fmax(ya, yb) + marg;
        const int ix0 = max(0, (int)floor(xlo * 8.0)), ix1 = min(7, (int)floor(xhi * 8.0));
        const int iy0 = max(0, (int)floor(ylo * 8.0)), iy1 = min(7, (int)floor(yhi * 8.0));
        if (ix0 <= ix1 && iy0 <= iy1) {
            ixlo = ix0; iylo = iy0;
            ny = iy1 - iy0 + 1;
            ncand = (ix1 - ix0 + 1) * ny * 24;
        }
    }

    double bt = 1e10;
    int    bi = 0x7fffffff;
    for (int c = lane; c < ncand; c += 64) {
        const int cell = c / 24, fk = c - cell * 24;
        const int cx = cell / ny, cy = cell - cx * ny;
        const int F = ((ixlo + cx) * 64 + (iylo + cy) * 8) * 24 + fk;
        const double t = mt_eval_f64(F, faces, sx, sy, sz, ox, oy, oz, dx, dy, dz);
        if (t < bt || (t == bt && F < bi)) { bt = t; bi = F; }
    }
    for (int off = 32; off; off >>= 1) {
        const double t2 = __shfl_down(bt, off);
        const int    i2 = __shfl_down(bi, off);
        if (t2 < bt || (t2 == bt && i2 < bi)) { bt = t2; bi = i2; }
    }
    const double btw = __shfl(bt, 0);
    if (btw >= 1e10) {                       // fallback: full scan (≈never)
        bt = 1e10; bi = 0x7fffffff;
        for (int F = lane; F < NF; F += 64) {
            const double t = mt_eval_f64(F, faces, sx, sy, sz, ox, oy, oz, dx, dy, dz);
            if (t < bt || (t == bt && F < bi)) { bt = t; bi = F; }
        }
        for (int off = 32; off; off >>= 1) {
            const double t2 = __shfl_down(bt, off);
            const int    i2 = __shfl_down(bi, off);
            if (t2 < bt || (t2 == bt && i2 < bi)) { bt = t2; bi = i2; }
        }
    }
    if (lane == 0) { tmin_out[r] = bt; fidx_out[r] = bi; }
}

// ---------------------------------------------------------------------------
// Kernel 2: per-ray walk with O(1) analytic segment jump.
// Within a tet, a_i(toff) is affine -> min_i a_i is CONCAVE -> the predicate
// region is an interval, so certifying the (bit-identical) per-k predicate at
// both segment endpoints certifies every interior k. Events (exact matvec +
// <=3 argmin moves) are round-6-identical; topo prefetched as int4.
// ---------------------------------------------------------------------------
__global__ __launch_bounds__(64) void walk_kernel(
    const float* __restrict__ ro,
    const float* __restrict__ rd,
    const int*   __restrict__ topo,
    const double* __restrict__ tmin_in,
    const int*    __restrict__ fidx_in,
    const double* __restrict__ winv,
    short* __restrict__ seq,
    float* __restrict__ out_tstart,
    float* __restrict__ out_tend,
    int R)
{
    const int r = blockIdx.x * 64 + threadIdx.x;
    if (r >= R) return;

    short* myseq = seq + (size_t)r * S_MAX;

    const double tmin = tmin_in[r];
    const bool   hit  = tmin < 5.0;
    const double t0   = hit ? tmin : 0.0;
    out_tstart[r] = (float)t0;
    out_tend[r]   = hit ? (float)(t0 + 0.05) : 0.0f;
    if (!hit) {
        for (int k = 0; k < S_MAX; ++k) myseq[k] = -1;
        return;
    }

    const double ox = (double)ro[3 * r + 0], oy = (double)ro[3 * r + 1], oz = (double)ro[3 * r + 2];
    const double dx = (double)rd[3 * r + 0], dy = (double)rd[3 * r + 1], dz = (double)rd[3 * r + 2];
    const double hpx = ox + t0 * dx, hpy = oy + t0 * dy, hpz = oz + t0 * dz;

    int  tet   = fidx_in[r] >> 2;
    bool alive = true;

    int4 topo4 = ((const int4*)topo)[tet];
    const double* rec = winv + 12 * (size_t)tet;
    double v0x = rec[0], v0y = rec[1], v0z = rec[2];
    double i0 = rec[3], i1 = rec[4],  i2 = rec[5];
    double i3 = rec[6], i4 = rec[7],  i5 = rec[8];
    double i6 = rec[9], i7 = rec[10], i8 = rec[11];

    double wb0, wb1, wb2, wb3, wd0, wd1, wd2, wd3;
    {
        const double bx = hpx - v0x, by = hpy - v0y, bz = hpz - v0z;
        wb1 = i0 * bx + i1 * by + i2 * bz;
        wb2 = i3 * bx + i4 * by + i5 * bz;
        wb3 = i6 * bx + i7 * by + i8 * bz;
        wd1 = i0 * dx + i1 * dy + i2 * dz;
        wd2 = i3 * dx + i4 * dy + i5 * dz;
        wd3 = i6 * dx + i7 * dy + i8 * dz;
        wb0 = 1.0 - (wb1 + wb2 + wb3);
        wd0 = -(wd1 + wd2 + wd3);
    }

    // per-k predicate — identical expressions to the round-6 fast-scan check
    auto Pk = [&](int kk) -> bool {
        const double toff = (double)kk * STEPD + 1e-4;
        const double a0 = wb0 + toff * wd0;
        const double a1 = wb1 + toff * wd1;
        const double a2 = wb2 + toff * wd2;
        const double a3 = wb3 + toff * wd3;
        const double mn = fmin(fmin(a0, a1), fmin(a2, a3));
        return (mn + 1e-6 >= GUARD);
    };

    int k = 0;
    while (k < S_MAX) {
        if (Pk(k)) {
            // analytic guess of the last in-segment k
            const double c = GUARD - 1e-6;
            double U = 1e30;
            if (wd0 < 0.0) U = fmin(U, (c - wb0) / wd0);
            if (wd1 < 0.0) U = fmin(U, (c - wb1) / wd1);
            if (wd2 < 0.0) U = fmin(U, (c - wb2) / wd2);
            if (wd3 < 0.0) U = fmin(U, (c - wb3) / wd3);
            int kh;
            if (U > 1e29) kh = S_MAX - 1;
            else {
                kh = (int)floor((U - 1e-4) * (128.0 / 0.05));
                if (kh > S_MAX - 1) kh = S_MAX - 1;
                if (kh < k) kh = k;
            }
            while (kh > k && !Pk(kh)) --kh;       // fp-guess adjust (<=1-2 iters)
            while (kh + 1 < S_MAX && Pk(kh + 1)) ++kh;
            const short st = (short)tet;
            for (int kk = k; kk <= kh; ++kk) myseq[kk] = st;
            k = kh + 1;
            if (k >= S_MAX) break;
            // fall through: Pk(k) false -> event
        }

        // ---- exact event at sample k (round-6-identical decision path) ----
        const double toff = (double)k * STEPD + 1e-4;
        const double px = hpx + toff * dx;
        const double py = hpy + toff * dy;
        const double pz = hpz + toff * dz;

        double b1 = px - v0x, b2 = py - v0y, b3 = pz - v0z;
        double w1 = i0 * b1 + i1 * b2 + i2 * b3;
        double w2 = i3 * b1 + i4 * b2 + i5 * b3;
        double w3 = i6 * b1 + i7 * b2 + i8 * b3;
        double w0 = 1.0 - (w1 + w2 + w3);
        bool inside = (w0 >= -1e-6) && (w1 >= -1e-6) && (w2 >= -1e-6) && (w3 >= -1e-6);

        int it = 0;
        bool moved = false;
        while (!inside && it < 3) {
            int    jm = 0;
            double wb = w0;
            if (w1 < wb) { wb = w1; jm = 1; }
            if (w2 < wb) { wb = w2; jm = 2; }
            if (w3 < wb) { wb = w3; jm = 3; }
            const int nb = (jm == 0) ? topo4.w : (jm == 1) ? topo4.z :
                           (jm == 2) ? topo4.y : topo4.x;          // topo[4*tet + 3-jm]
            if (nb < 0) { alive = false; break; }
            tet = nb;
            moved = true;
            rec = winv + 12 * (size_t)tet;
            topo4 = ((const int4*)topo)[tet];     // concurrent with winv loads
            v0x = rec[0]; v0y = rec[1]; v0z = rec[2];
            i0 = rec[3]; i1 = rec[4];  i2 = rec[5];
            i3 = rec[6]; i4 = rec[7];  i5 = rec[8];
            i6 = rec[9]; i7 = rec[10]; i8 = rec[11];
            b1 = px - v0x; b2 = py - v0y; b3 = pz - v0z;
            w1 = i0 * b1 + i1 * b2 + i2 * b3;
            w2 = i3 * b1 + i4 * b2 + i5 * b3;
            w3 = i6 * b1 + i7 * b2 + i8 * b3;
            w0 = 1.0 - (w1 + w2 + w3);
            inside = (w0 >= -1e-6) && (w1 >= -1e-6) && (w2 >= -1e-6) && (w3 >= -1e-6);
            ++it;
        }
        if (!alive) break;

        myseq[k] = inside ? (short)tet : (short)-1;
        ++k;

        if (moved) {
            const double bx = hpx - v0x, by = hpy - v0y, bz = hpz - v0z;
            wb1 = i0 * bx + i1 * by + i2 * bz;
            wb2 = i3 * bx + i4 * by + i5 * bz;
            wb3 = i6 * bx + i7 * by + i8 * bz;
            wd1 = i0 * dx + i1 * dy + i2 * dz;
            wd2 = i3 * dx + i4 * dy + i5 * dz;
            wd3 = i6 * dx + i7 * dy + i8 * dz;
            wb0 = 1.0 - (wb1 + wb2 + wb3);
            wd0 = -(wd1 + wd2 + wd3);
        }
    }
    for (; k < S_MAX; ++k) myseq[k] = -1;
}

// ---------------------------------------------------------------------------
// Kernel 3: parallel emission, coalesced writes, precomputed inv.
// ---------------------------------------------------------------------------
__global__ __launch_bounds__(256) void emit_kernel(
    const float* __restrict__ ro,
    const float* __restrict__ rd,
    const double* __restrict__ tmin_in,
    const short*  __restrict__ seq,
    const double* __restrict__ winv,
    float* __restrict__ out_rayidx,
    float* __restrict__ out_tetidx,
    float* __restrict__ out_bary,
    float* __restrict__ out_pos,
    int R)
{
    const int idx = blockIdx.x * 256 + threadIdx.x;
    if (idx >= R * S_MAX) return;
    const int r = idx >> 7;
    const int k = idx & (S_MAX - 1);

    const int tk = (int)seq[idx];
    if (tk < 0) {
        out_rayidx[idx] = -1.0f;
        out_tetidx[idx] = -1.0f;
        ((float4*)out_bary)[idx] = make_float4(0.0f, 0.0f, 0.0f, 0.0f);
        out_pos[idx * 3 + 0] = 0.0f;
        out_pos[idx * 3 + 1] = 0.0f;
        out_pos[idx * 3 + 2] = 0.0f;
        return;
    }

    const double tmin = tmin_in[r];
    const double t0   = (tmin < 5.0) ? tmin : 0.0;
    const double ox = (double)ro[3 * r + 0], oy = (double)ro[3 * r + 1], oz = (double)ro[3 * r + 2];
    const double dx = (double)rd[3 * r + 0], dy = (double)rd[3 * r + 1], dz = (double)rd[3 * r + 2];
    const double toff = (double)k * STEPD + 1e-4;
    const double px = (ox + t0 * dx) + toff * dx;
    const double py = (oy + t0 * dy) + toff * dy;
    const double pz = (oz + t0 * dz) + toff * dz;

    const double* rec = winv + 12 * (size_t)tk;
    const double b1 = px - rec[0], b2 = py - rec[1], b3 = pz - rec[2];
    const double w1 = rec[3] * b1 + rec[4]  * b2 + rec[5]  * b3;
    const double w2 = rec[6] * b1 + rec[7]  * b2 + rec[8]  * b3;
    const double w3 = rec[9] * b1 + rec[10] * b2 + rec[11] * b3;
    const double w0 = 1.0 - (w1 + w2 + w3);

    out_rayidx[idx] = (float)r;
    out_tetidx[idx] = (float)tk;
    ((float4*)out_bary)[idx] = make_float4((float)w0, (float)w1, (float)w2, (float)w3);
    out_pos[idx * 3 + 0] = (float)px;
    out_pos[idx * 3 + 1] = (float)py;
    out_pos[idx * 3 + 2] = (float)pz;
}

extern "C" void kernel_launch(void* const* d_in, const int* in_sizes, int n_in,
                              void* d_out, int out_size, void* d_ws, size_t ws_size,
                              hipStream_t stream) {
    const float* verts  = (const float*)d_in[0];
    const float* ro     = (const float*)d_in[1];
    const float* rd     = (const float*)d_in[2];
    const int*   tetras = (const int*)d_in[3];
    const int*   faces  = (const int*)d_in[4];
    const int*   topo   = (const int*)d_in[5];

    const int NV = in_sizes[0] / 3;
    const int R  = in_sizes[1] / 3;
    const int NT = in_sizes[3] / 4;
    const int NF = in_sizes[4] / 3;
    const int S  = S_MAX;

    // ws layout (8B-aligned first): tmin f64[R] | inv f64[12*NT] | bnd f32[4] | fidx i32[R] | seq i16[R*S]
    double* wtmin = (double*)d_ws;
    double* winv  = wtmin + R;
    float*  wbnd  = (float*)(winv + 12 * (size_t)NT);
    int*    wfidx = (int*)(wbnd + 4);
    short*  wseq  = (short*)(wfidx + R);

    float* out        = (float*)d_out;
    float* out_rayidx = out;
    float* out_tetidx = out + (size_t)R * S;
    float* out_bary   = out + (size_t)2 * R * S;
    float* out_tstart = out + (size_t)6 * R * S;
    float* out_tend   = out_tstart + R;
    float* out_pos    = out_tend + R;

    prep_kernel<<<(NT + 255) / 256, 256, 0, stream>>>(verts, tetras, winv, wbnd, NV, NT);
    isect_kernel<<<(R + 3) / 4, 256, 0, stream>>>(verts, ro, rd, faces, wbnd, wtmin, wfidx, NV, NF, R);
    walk_kernel<<<(R + 63) / 64, 64, 0, stream>>>(ro, rd, topo, wtmin, wfidx, winv,
                                                  wseq, out_tstart, out_tend, R);
    emit_kernel<<<(R * S + 255) / 256, 256, 0, stream>>>(ro, rd, wtmin, wseq, winv,
                                                         out_rayidx, out_tetidx, out_bary, out_pos, R);
}

// Round 8
// 87.503 us; speedup vs baseline: 3.4240x; 1.1317x over previous
//
#include <hip/hip_runtime.h>

#define S_MAX 128
#define NV_MAX 729
#define STEPD (0.05 / 128.0)
#define GUARD 1e-12

// ---------------------------------------------------------------------------
// Exact f64 Moller-Trumbore for face F (round-3-identical). Returns t or 1e10.
// ---------------------------------------------------------------------------
static __device__ __forceinline__ double mt_eval_f64(
    int F, const int* __restrict__ faces,
    const float* sx, const float* sy, const float* sz,
    double ox, double oy, double oz,
    double dx, double dy, double dz)
{
    const int i0 = faces[3 * F + 0];
    const int i1 = faces[3 * F + 1];
    const int i2 = faces[3 * F + 2];
    const double p0x = (double)sx[i0], p0y = (double)sy[i0], p0z = (double)sz[i0];
    const double e1x = (double)sx[i1] - p0x, e1y = (double)sy[i1] - p0y, e1z = (double)sz[i1] - p0z;
    const double e2x = (double)sx[i2] - p0x, e2y = (double)sy[i2] - p0y, e2z = (double)sz[i2] - p0z;
    const double hx = dy * e2z - dz * e2y;
    const double hy = dz * e2x - dx * e2z;
    const double hz = dx * e2y - dy * e2x;
    const double a  = e1x * hx + e1y * hy + e1z * hz;
    const bool oka = fabs(a) > 1e-9;
    const double f  = 1.0 / (oka ? a : 1e-9);
    const double s0 = ox - p0x, s1 = oy - p0y, s2 = oz - p0z;
    const double u  = f * (s0 * hx + s1 * hy + s2 * hz);
    const double qx = s1 * e1z - s2 * e1y;
    const double qy = s2 * e1x - s0 * e1z;
    const double qz = s0 * e1y - s1 * e1x;
    const double v  = f * (dx * qx + dy * qy + dz * qz);
    double t        = f * (e2x * qx + e2y * qy + e2z * qz);
    const bool ok = oka && (u >= 0.0) && (u <= 1.0) && (v >= 0.0) &&
                    (u + v <= 1.0) && (t > 1e-6);
    return ok ? t : 1e10;
}

// ---------------------------------------------------------------------------
// Kernel 1 (fused): blocks [0, nIsect) = per-ray first hit (one wave per ray,
// locally-computed mesh bounds, candidate layer-0 cells, full-scan fallback);
// blocks [nIsect, nIsect+nPrep) = per-tet {v0, inv(M)} f64 precompute.
// winv layout: 12 doubles per tet.
// ---------------------------------------------------------------------------
__global__ __launch_bounds__(256) void isect_prep_kernel(
    const float* __restrict__ verts,
    const float* __restrict__ ro,
    const float* __restrict__ rd,
    const int*   __restrict__ faces,
    const int*   __restrict__ tetras,
    double* __restrict__ winv,
    double* __restrict__ tmin_out,
    int*    __restrict__ fidx_out,
    int NV, int NT, int NF, int R, int nIsect)
{
    const int tid = threadIdx.x;

    if (blockIdx.x >= nIsect) {
        // ---- prep part: per-tet inverse ----
        const int t = (blockIdx.x - nIsect) * 256 + tid;
        if (t < NT) {
            const int4 tv = ((const int4*)tetras)[t];
            const double v0x = (double)verts[3 * tv.x + 0];
            const double v0y = (double)verts[3 * tv.x + 1];
            const double v0z = (double)verts[3 * tv.x + 2];
            const double m11 = (double)verts[3 * tv.y + 0] - v0x, m21 = (double)verts[3 * tv.y + 1] - v0y, m31 = (double)verts[3 * tv.y + 2] - v0z;
            const double m12 = (double)verts[3 * tv.z + 0] - v0x, m22 = (double)verts[3 * tv.z + 1] - v0y, m32 = (double)verts[3 * tv.z + 2] - v0z;
            const double m13 = (double)verts[3 * tv.w + 0] - v0x, m23 = (double)verts[3 * tv.w + 1] - v0y, m33 = (double)verts[3 * tv.w + 2] - v0z;
            const double A = m22 * m33 - m23 * m32;
            const double B = m21 * m33 - m23 * m31;
            const double C = m21 * m32 - m22 * m31;
            const double det = m11 * A - m12 * B + m13 * C;
            const double rcp = 1.0 / det;
            double* o = winv + 12 * (size_t)t;
            o[0] = v0x; o[1] = v0y; o[2] = v0z;
            o[3]  = A * rcp;  o[4]  = (m13 * m32 - m12 * m33) * rcp;  o[5]  = (m12 * m23 - m13 * m22) * rcp;
            o[6]  = -B * rcp; o[7]  = (m11 * m33 - m13 * m31) * rcp;  o[8]  = (m13 * m21 - m11 * m23) * rcp;
            o[9]  = C * rcp;  o[10] = (m12 * m31 - m11 * m32) * rcp;  o[11] = (m11 * m22 - m12 * m21) * rcp;
        }
        return;
    }

    // ---- isect part ----
    __shared__ float sx[NV_MAX], sy[NV_MAX], sz[NV_MAX];
    __shared__ float red[256];
    __shared__ float s_zmin, s_zmax, s_marg;

    for (int i = tid; i < NV; i += 256) {
        sx[i] = verts[3 * i + 0];
        sy[i] = verts[3 * i + 1];
        sz[i] = verts[3 * i + 2];
    }
    __syncthreads();

    float zmin = 1e9f, zmax = -1e9f, dev = 0.0f;
    for (int i = tid; i < NV; i += 256) {
        const float x = sx[i], y = sy[i], z = sz[i];
        if (i % 9 == 0) { zmin = fminf(zmin, z); zmax = fmaxf(zmax, z); }
        dev = fmaxf(dev, fabsf(x - rintf(x * 8.0f) * 0.125f));
        dev = fmaxf(dev, fabsf(y - rintf(y * 8.0f) * 0.125f));
    }
    red[tid] = zmin; __syncthreads();
    for (int s = 128; s; s >>= 1) { if (tid < s) red[tid] = fminf(red[tid], red[tid + s]); __syncthreads(); }
    if (tid == 0) s_zmin = red[0];
    __syncthreads();
    red[tid] = zmax; __syncthreads();
    for (int s = 128; s; s >>= 1) { if (tid < s) red[tid] = fmaxf(red[tid], red[tid + s]); __syncthreads(); }
    if (tid == 0) s_zmax = red[0];
    __syncthreads();
    red[tid] = dev; __syncthreads();
    for (int s = 128; s; s >>= 1) { if (tid < s) red[tid] = fmaxf(red[tid], red[tid + s]); __syncthreads(); }
    if (tid == 0) s_marg = red[0] + 1e-5f;
    __syncthreads();

    const int wv = tid >> 6, lane = tid & 63;
    const int r = blockIdx.x * 4 + wv;
    if (r >= R) return;

    const double ox = (double)ro[3 * r + 0], oy = (double)ro[3 * r + 1], oz = (double)ro[3 * r + 2];
    const double dx = (double)rd[3 * r + 0], dy = (double)rd[3 * r + 1], dz = (double)rd[3 * r + 2];

    int ncand = 0, ixlo = 0, iylo = 0, ny = 1;
    if (dz > 0.0) {
        const double t_lo = ((double)s_zmin - oz) / dz;
        const double t_hi = ((double)s_zmax - oz) / dz;
        const double marg = (double)s_marg + 1e-9;
        const double xa = ox + t_lo * dx, xb = ox + t_hi * dx;
        const double ya = oy + t_lo * dy, yb = oy + t_hi * dy;
        const double xlo = fmin(xa, xb) - marg, xhi = fmax(xa, xb) + marg;
        const double ylo = fmin(ya, yb) - marg, yhi = fmax(ya, yb) + marg;
        const int ix0 = max(0, (int)floor(xlo * 8.0)), ix1 = min(7, (int)floor(xhi * 8.0));
        const int iy0 = max(0, (int)floor(ylo * 8.0)), iy1 = min(7, (int)floor(yhi * 8.0));
        if (ix0 <= ix1 && iy0 <= iy1) {
            ixlo = ix0; iylo = iy0;
            ny = iy1 - iy0 + 1;
            ncand = (ix1 - ix0 + 1) * ny * 24;
        }
    }

    double bt = 1e10;
    int    bi = 0x7fffffff;
    for (int c = lane; c < ncand; c += 64) {
        const int cell = c / 24, fk = c - cell * 24;
        const int cx = cell / ny, cy = cell - cx * ny;
        const int F = ((ixlo + cx) * 64 + (iylo + cy) * 8) * 24 + fk;
        const double t = mt_eval_f64(F, faces, sx, sy, sz, ox, oy, oz, dx, dy, dz);
        if (t < bt || (t == bt && F < bi)) { bt = t; bi = F; }
    }
    for (int off = 32; off; off >>= 1) {
        const double t2 = __shfl_down(bt, off);
        const int    i2 = __shfl_down(bi, off);
        if (t2 < bt || (t2 == bt && i2 < bi)) { bt = t2; bi = i2; }
    }
    const double btw = __shfl(bt, 0);
    if (btw >= 1e10) {                       // fallback: full scan (≈never)
        bt = 1e10; bi = 0x7fffffff;
        for (int F = lane; F < NF; F += 64) {
            const double t = mt_eval_f64(F, faces, sx, sy, sz, ox, oy, oz, dx, dy, dz);
            if (t < bt || (t == bt && F < bi)) { bt = t; bi = F; }
        }
        for (int off = 32; off; off >>= 1) {
            const double t2 = __shfl_down(bt, off);
            const int    i2 = __shfl_down(bi, off);
            if (t2 < bt || (t2 == bt && i2 < bi)) { bt = t2; bi = i2; }
        }
    }
    if (lane == 0) { tmin_out[r] = bt; fidx_out[r] = bi; }
}

// ---------------------------------------------------------------------------
// Kernel 2: ONE WAVE PER RAY walk. 64 lanes evaluate the (bit-identical)
// per-k predicate at 64 consecutive samples; __ballot finds the first event;
// segment stores are coalesced. Events run redundantly-uniform on all lanes
// (broadcast loads). Decision path expression-identical to round 7.
// ---------------------------------------------------------------------------
__global__ __launch_bounds__(256) void walk_kernel(
    const float* __restrict__ ro,
    const float* __restrict__ rd,
    const int*   __restrict__ topo,
    const double* __restrict__ tmin_in,
    const int*    __restrict__ fidx_in,
    const double* __restrict__ winv,
    short* __restrict__ seq,
    float* __restrict__ out_tstart,
    float* __restrict__ out_tend,
    int R)
{
    const int wv = threadIdx.x >> 6, lane = threadIdx.x & 63;
    const int r = blockIdx.x * 4 + wv;
    if (r >= R) return;

    short* myseq = seq + (size_t)r * S_MAX;

    const double tmin = tmin_in[r];
    const bool   hit  = tmin < 5.0;
    const double t0   = hit ? tmin : 0.0;
    if (lane == 0) {
        out_tstart[r] = (float)t0;
        out_tend[r]   = hit ? (float)(t0 + 0.05) : 0.0f;
    }
    if (!hit) {
        for (int k = lane; k < S_MAX; k += 64) myseq[k] = -1;
        return;
    }

    const double ox = (double)ro[3 * r + 0], oy = (double)ro[3 * r + 1], oz = (double)ro[3 * r + 2];
    const double dx = (double)rd[3 * r + 0], dy = (double)rd[3 * r + 1], dz = (double)rd[3 * r + 2];
    const double hpx = ox + t0 * dx, hpy = oy + t0 * dy, hpz = oz + t0 * dz;

    int  tet   = fidx_in[r] >> 2;
    bool alive = true;

    int4 topo4 = ((const int4*)topo)[tet];
    const double* rec = winv + 12 * (size_t)tet;
    double v0x = rec[0], v0y = rec[1], v0z = rec[2];
    double i0 = rec[3], i1 = rec[4],  i2 = rec[5];
    double i3 = rec[6], i4 = rec[7],  i5 = rec[8];
    double i6 = rec[9], i7 = rec[10], i8 = rec[11];

    double wb0, wb1, wb2, wb3, wd0, wd1, wd2, wd3;
    {
        const double bx = hpx - v0x, by = hpy - v0y, bz = hpz - v0z;
        wb1 = i0 * bx + i1 * by + i2 * bz;
        wb2 = i3 * bx + i4 * by + i5 * bz;
        wb3 = i6 * bx + i7 * by + i8 * bz;
        wd1 = i0 * dx + i1 * dy + i2 * dz;
        wd2 = i3 * dx + i4 * dy + i5 * dz;
        wd3 = i6 * dx + i7 * dy + i8 * dz;
        wb0 = 1.0 - (wb1 + wb2 + wb3);
        wd0 = -(wd1 + wd2 + wd3);
    }

    int k0 = 0;
    while (k0 < S_MAX) {
        // ---- parallel predicate window: lane evaluates k0+lane ----
        const int kk = k0 + lane;
        bool p = false;
        if (kk < S_MAX) {
            const double toff = (double)kk * STEPD + 1e-4;
            const double a0 = wb0 + toff * wd0;
            const double a1 = wb1 + toff * wd1;
            const double a2 = wb2 + toff * wd2;
            const double a3 = wb3 + toff * wd3;
            const double mn = fmin(fmin(a0, a1), fmin(a2, a3));
            p = (mn + 1e-6 >= GUARD);
        }
        const unsigned long long bad = __ballot(kk < S_MAX && !p);
        const int nvalid = min(S_MAX - k0, 64);
        const int evt = (bad == 0ull) ? nvalid : (__ffsll(bad) - 1);

        if (lane < evt) myseq[kk] = (short)tet;    // coalesced segment store
        k0 += evt;
        if (evt == nvalid) continue;               // window exhausted (or done)

        // ---- exact event at sample k0 (uniform across lanes; round-7-identical)
        const double toff = (double)k0 * STEPD + 1e-4;
        const double px = hpx + toff * dx;
        const double py = hpy + toff * dy;
        const double pz = hpz + toff * dz;

        double b1 = px - v0x, b2 = py - v0y, b3 = pz - v0z;
        double w1 = i0 * b1 + i1 * b2 + i2 * b3;
        double w2 = i3 * b1 + i4 * b2 + i5 * b3;
        double w3 = i6 * b1 + i7 * b2 + i8 * b3;
        double w0 = 1.0 - (w1 + w2 + w3);
        bool inside = (w0 >= -1e-6) && (w1 >= -1e-6) && (w2 >= -1e-6) && (w3 >= -1e-6);

        int it = 0;
        bool moved = false;
        while (!inside && it < 3) {
            int    jm = 0;
            double wb = w0;
            if (w1 < wb) { wb = w1; jm = 1; }
            if (w2 < wb) { wb = w2; jm = 2; }
            if (w3 < wb) { wb = w3; jm = 3; }
            const int nb = (jm == 0) ? topo4.w : (jm == 1) ? topo4.z :
                           (jm == 2) ? topo4.y : topo4.x;
            if (nb < 0) { alive = false; break; }
            tet = nb;
            moved = true;
            rec = winv + 12 * (size_t)tet;
            topo4 = ((const int4*)topo)[tet];
            v0x = rec[0]; v0y = rec[1]; v0z = rec[2];
            i0 = rec[3]; i1 = rec[4];  i2 = rec[5];
            i3 = rec[6]; i4 = rec[7];  i5 = rec[8];
            i6 = rec[9]; i7 = rec[10]; i8 = rec[11];
            b1 = px - v0x; b2 = py - v0y; b3 = pz - v0z;
            w1 = i0 * b1 + i1 * b2 + i2 * b3;
            w2 = i3 * b1 + i4 * b2 + i5 * b3;
            w3 = i6 * b1 + i7 * b2 + i8 * b3;
            w0 = 1.0 - (w1 + w2 + w3);
            inside = (w0 >= -1e-6) && (w1 >= -1e-6) && (w2 >= -1e-6) && (w3 >= -1e-6);
            ++it;
        }
        if (!alive) break;

        if (lane == 0) myseq[k0] = inside ? (short)tet : (short)-1;
        ++k0;

        if (moved) {
            const double bx = hpx - v0x, by = hpy - v0y, bz = hpz - v0z;
            wb1 = i0 * bx + i1 * by + i2 * bz;
            wb2 = i3 * bx + i4 * by + i5 * bz;
            wb3 = i6 * bx + i7 * by + i8 * bz;
            wd1 = i0 * dx + i1 * dy + i2 * dz;
            wd2 = i3 * dx + i4 * dy + i5 * dz;
            wd3 = i6 * dx + i7 * dy + i8 * dz;
            wb0 = 1.0 - (wb1 + wb2 + wb3);
            wd0 = -(wd1 + wd2 + wd3);
        }
    }
    for (int k = k0 + lane; k < S_MAX; k += 64) myseq[k] = -1;
}

// ---------------------------------------------------------------------------
// Kernel 3: parallel emission, coalesced writes, precomputed inv.
// ---------------------------------------------------------------------------
__global__ __launch_bounds__(256) void emit_kernel(
    const float* __restrict__ ro,
    const float* __restrict__ rd,
    const double* __restrict__ tmin_in,
    const short*  __restrict__ seq,
    const double* __restrict__ winv,
    float* __restrict__ out_rayidx,
    float* __restrict__ out_tetidx,
    float* __restrict__ out_bary,
    float* __restrict__ out_pos,
    int R)
{
    const int idx = blockIdx.x * 256 + threadIdx.x;
    if (idx >= R * S_MAX) return;
    const int r = idx >> 7;
    const int k = idx & (S_MAX - 1);

    const int tk = (int)seq[idx];
    if (tk < 0) {
        out_rayidx[idx] = -1.0f;
        out_tetidx[idx] = -1.0f;
        ((float4*)out_bary)[idx] = make_float4(0.0f, 0.0f, 0.0f, 0.0f);
        out_pos[idx * 3 + 0] = 0.0f;
        out_pos[idx * 3 + 1] = 0.0f;
        out_pos[idx * 3 + 2] = 0.0f;
        return;
    }

    const double tmin = tmin_in[r];
    const double t0   = (tmin < 5.0) ? tmin : 0.0;
    const double ox = (double)ro[3 * r + 0], oy = (double)ro[3 * r + 1], oz = (double)ro[3 * r + 2];
    const double dx = (double)rd[3 * r + 0], dy = (double)rd[3 * r + 1], dz = (double)rd[3 * r + 2];
    const double toff = (double)k * STEPD + 1e-4;
    const double px = (ox + t0 * dx) + toff * dx;
    const double py = (oy + t0 * dy) + toff * dy;
    const double pz = (oz + t0 * dz) + toff * dz;

    const double* rec = winv + 12 * (size_t)tk;
    const double b1 = px - rec[0], b2 = py - rec[1], b3 = pz - rec[2];
    const double w1 = rec[3] * b1 + rec[4]  * b2 + rec[5]  * b3;
    const double w2 = rec[6] * b1 + rec[7]  * b2 + rec[8]  * b3;
    const double w3 = rec[9] * b1 + rec[10] * b2 + rec[11] * b3;
    const double w0 = 1.0 - (w1 + w2 + w3);

    out_rayidx[idx] = (float)r;
    out_tetidx[idx] = (float)tk;
    ((float4*)out_bary)[idx] = make_float4((float)w0, (float)w1, (float)w2, (float)w3);
    out_pos[idx * 3 + 0] = (float)px;
    out_pos[idx * 3 + 1] = (float)py;
    out_pos[idx * 3 + 2] = (float)pz;
}

extern "C" void kernel_launch(void* const* d_in, const int* in_sizes, int n_in,
                              void* d_out, int out_size, void* d_ws, size_t ws_size,
                              hipStream_t stream) {
    const float* verts  = (const float*)d_in[0];
    const float* ro     = (const float*)d_in[1];
    const float* rd     = (const float*)d_in[2];
    const int*   tetras = (const int*)d_in[3];
    const int*   faces  = (const int*)d_in[4];
    const int*   topo   = (const int*)d_in[5];

    const int NV = in_sizes[0] / 3;
    const int R  = in_sizes[1] / 3;
    const int NT = in_sizes[3] / 4;
    const int NF = in_sizes[4] / 3;
    const int S  = S_MAX;

    // ws layout (8B-aligned first): tmin f64[R] | inv f64[12*NT] | fidx i32[R] | seq i16[R*S]
    double* wtmin = (double*)d_ws;
    double* winv  = wtmin + R;
    int*    wfidx = (int*)(winv + 12 * (size_t)NT);
    short*  wseq  = (short*)(wfidx + R);

    float* out        = (float*)d_out;
    float* out_rayidx = out;
    float* out_tetidx = out + (size_t)R * S;
    float* out_bary   = out + (size_t)2 * R * S;
    float* out_tstart = out + (size_t)6 * R * S;
    float* out_tend   = out_tstart + R;
    float* out_pos    = out_tend + R;

    const int nIsect = (R + 3) / 4;
    const int nPrep  = (NT + 255) / 256;

    isect_prep_kernel<<<nIsect + nPrep, 256, 0, stream>>>(
        verts, ro, rd, faces, tetras, winv, wtmin, wfidx, NV, NT, NF, R, nIsect);
    walk_kernel<<<(R + 3) / 4, 256, 0, stream>>>(ro, rd, topo, wtmin, wfidx, winv,
                                                 wseq, out_tstart, out_tend, R);
    emit_kernel<<<(R * S + 255) / 256, 256, 0, stream>>>(ro, rd, wtmin, wseq, winv,
                                                         out_rayidx, out_tetidx, out_bary, out_pos, R);
}

// Round 9
// 83.404 us; speedup vs baseline: 3.5923x; 1.0491x over previous
//
#include <hip/hip_runtime.h>

#define S_MAX 128
#define NV_MAX 729
#define STEPD (0.05 / 128.0)
#define GUARD 1e-12

// ---------------------------------------------------------------------------
// Exact f64 Moller-Trumbore for face F (round-3-identical). Returns t or 1e10.
// ---------------------------------------------------------------------------
static __device__ __forceinline__ double mt_eval_f64(
    int F, const int* __restrict__ faces,
    const float* sx, const float* sy, const float* sz,
    double ox, double oy, double oz,
    double dx, double dy, double dz)
{
    const int i0 = faces[3 * F + 0];
    const int i1 = faces[3 * F + 1];
    const int i2 = faces[3 * F + 2];
    const double p0x = (double)sx[i0], p0y = (double)sy[i0], p0z = (double)sz[i0];
    const double e1x = (double)sx[i1] - p0x, e1y = (double)sy[i1] - p0y, e1z = (double)sz[i1] - p0z;
    const double e2x = (double)sx[i2] - p0x, e2y = (double)sy[i2] - p0y, e2z = (double)sz[i2] - p0z;
    const double hx = dy * e2z - dz * e2y;
    const double hy = dz * e2x - dx * e2z;
    const double hz = dx * e2y - dy * e2x;
    const double a  = e1x * hx + e1y * hy + e1z * hz;
    const bool oka = fabs(a) > 1e-9;
    const double f  = 1.0 / (oka ? a : 1e-9);
    const double s0 = ox - p0x, s1 = oy - p0y, s2 = oz - p0z;
    const double u  = f * (s0 * hx + s1 * hy + s2 * hz);
    const double qx = s1 * e1z - s2 * e1y;
    const double qy = s2 * e1x - s0 * e1z;
    const double qz = s0 * e1y - s1 * e1x;
    const double v  = f * (dx * qx + dy * qy + dz * qz);
    double t        = f * (e2x * qx + e2y * qy + e2z * qz);
    const bool ok = oka && (u >= 0.0) && (u <= 1.0) && (v >= 0.0) &&
                    (u + v <= 1.0) && (t > 1e-6);
    return ok ? t : 1e10;
}

// ---------------------------------------------------------------------------
// Kernel 0: per-tet {v0, inv(M)} f64 precompute (round-8-identical exprs).
// winv layout: 12 doubles per tet.
// ---------------------------------------------------------------------------
__global__ __launch_bounds__(256) void prep_kernel(
    const float* __restrict__ verts,
    const int*   __restrict__ tetras,
    double* __restrict__ winv,
    int NT)
{
    const int t = blockIdx.x * 256 + threadIdx.x;
    if (t >= NT) return;
    const int4 tv = ((const int4*)tetras)[t];
    const double v0x = (double)verts[3 * tv.x + 0];
    const double v0y = (double)verts[3 * tv.x + 1];
    const double v0z = (double)verts[3 * tv.x + 2];
    const double m11 = (double)verts[3 * tv.y + 0] - v0x, m21 = (double)verts[3 * tv.y + 1] - v0y, m31 = (double)verts[3 * tv.y + 2] - v0z;
    const double m12 = (double)verts[3 * tv.z + 0] - v0x, m22 = (double)verts[3 * tv.z + 1] - v0y, m32 = (double)verts[3 * tv.z + 2] - v0z;
    const double m13 = (double)verts[3 * tv.w + 0] - v0x, m23 = (double)verts[3 * tv.w + 1] - v0y, m33 = (double)verts[3 * tv.w + 2] - v0z;
    const double A = m22 * m33 - m23 * m32;
    const double B = m21 * m33 - m23 * m31;
    const double C = m21 * m32 - m22 * m31;
    const double det = m11 * A - m12 * B + m13 * C;
    const double rcp = 1.0 / det;
    double* o = winv + 12 * (size_t)t;
    o[0] = v0x; o[1] = v0y; o[2] = v0z;
    o[3]  = A * rcp;  o[4]  = (m13 * m32 - m12 * m33) * rcp;  o[5]  = (m12 * m23 - m13 * m22) * rcp;
    o[6]  = -B * rcp; o[7]  = (m11 * m33 - m13 * m31) * rcp;  o[8]  = (m13 * m21 - m11 * m23) * rcp;
    o[9]  = C * rcp;  o[10] = (m12 * m31 - m11 * m32) * rcp;  o[11] = (m11 * m22 - m12 * m21) * rcp;
}

// ---------------------------------------------------------------------------
// Kernel 1 (fused, one wave per ray): isect (R8-identical) -> ballot walk
// (R8-identical, seq in LDS) -> emit (R8-identical expressions, 2 samples
// per lane, coalesced stores). All decision/output expressions bit-identical
// to round 8.
// ---------------------------------------------------------------------------
__global__ __launch_bounds__(256) void fused_kernel(
    const float* __restrict__ verts,
    const float* __restrict__ ro,
    const float* __restrict__ rd,
    const int*   __restrict__ faces,
    const int*   __restrict__ topo,
    const double* __restrict__ winv,
    float* __restrict__ out_rayidx,
    float* __restrict__ out_tetidx,
    float* __restrict__ out_bary,
    float* __restrict__ out_tstart,
    float* __restrict__ out_tend,
    float* __restrict__ out_pos,
    int NV, int NF, int R)
{
    __shared__ float sx[NV_MAX], sy[NV_MAX], sz[NV_MAX];
    __shared__ float red[256];
    __shared__ float s_zmin, s_zmax, s_marg;
    __shared__ short s_seq[4][S_MAX];

    const int tid = threadIdx.x;
    for (int i = tid; i < NV; i += 256) {
        sx[i] = verts[3 * i + 0];
        sy[i] = verts[3 * i + 1];
        sz[i] = verts[3 * i + 2];
    }
    __syncthreads();

    // ---- mesh bounds (block-uniform) ----
    float zmin = 1e9f, zmax = -1e9f, dev = 0.0f;
    for (int i = tid; i < NV; i += 256) {
        const float x = sx[i], y = sy[i], z = sz[i];
        if (i % 9 == 0) { zmin = fminf(zmin, z); zmax = fmaxf(zmax, z); }
        dev = fmaxf(dev, fabsf(x - rintf(x * 8.0f) * 0.125f));
        dev = fmaxf(dev, fabsf(y - rintf(y * 8.0f) * 0.125f));
    }
    red[tid] = zmin; __syncthreads();
    for (int s = 128; s; s >>= 1) { if (tid < s) red[tid] = fminf(red[tid], red[tid + s]); __syncthreads(); }
    if (tid == 0) s_zmin = red[0];
    __syncthreads();
    red[tid] = zmax; __syncthreads();
    for (int s = 128; s; s >>= 1) { if (tid < s) red[tid] = fmaxf(red[tid], red[tid + s]); __syncthreads(); }
    if (tid == 0) s_zmax = red[0];
    __syncthreads();
    red[tid] = dev; __syncthreads();
    for (int s = 128; s; s >>= 1) { if (tid < s) red[tid] = fmaxf(red[tid], red[tid + s]); __syncthreads(); }
    if (tid == 0) s_marg = red[0] + 1e-5f;
    __syncthreads();

    const int wv = tid >> 6, lane = tid & 63;
    const int r = blockIdx.x * 4 + wv;
    if (r >= R) return;
    short* myseq = s_seq[wv];

    const double ox = (double)ro[3 * r + 0], oy = (double)ro[3 * r + 1], oz = (double)ro[3 * r + 2];
    const double dx = (double)rd[3 * r + 0], dy = (double)rd[3 * r + 1], dz = (double)rd[3 * r + 2];

    // ================= phase 1: first hit (R8-identical) =================
    int ncand = 0, ixlo = 0, iylo = 0, ny = 1;
    if (dz > 0.0) {
        const double t_lo = ((double)s_zmin - oz) / dz;
        const double t_hi = ((double)s_zmax - oz) / dz;
        const double marg = (double)s_marg + 1e-9;
        const double xa = ox + t_lo * dx, xb = ox + t_hi * dx;
        const double ya = oy + t_lo * dy, yb = oy + t_hi * dy;
        const double xlo = fmin(xa, xb) - marg, xhi = fmax(xa, xb) + marg;
        const double ylo = fmin(ya, yb) - marg, yhi = fmax(ya, yb) + marg;
        const int ix0 = max(0, (int)floor(xlo * 8.0)), ix1 = min(7, (int)floor(xhi * 8.0));
        const int iy0 = max(0, (int)floor(ylo * 8.0)), iy1 = min(7, (int)floor(yhi * 8.0));
        if (ix0 <= ix1 && iy0 <= iy1) {
            ixlo = ix0; iylo = iy0;
            ny = iy1 - iy0 + 1;
            ncand = (ix1 - ix0 + 1) * ny * 24;
        }
    }

    double bt = 1e10;
    int    bi = 0x7fffffff;
    for (int c = lane; c < ncand; c += 64) {
        const int cell = c / 24, fk = c - cell * 24;
        const int cx = cell / ny, cy = cell - cx * ny;
        const int F = ((ixlo + cx) * 64 + (iylo + cy) * 8) * 24 + fk;
        const double t = mt_eval_f64(F, faces, sx, sy, sz, ox, oy, oz, dx, dy, dz);
        if (t < bt || (t == bt && F < bi)) { bt = t; bi = F; }
    }
    for (int off = 32; off; off >>= 1) {
        const double t2 = __shfl_down(bt, off);
        const int    i2 = __shfl_down(bi, off);
        if (t2 < bt || (t2 == bt && i2 < bi)) { bt = t2; bi = i2; }
    }
    bt = __shfl(bt, 0);
    bi = __shfl(bi, 0);
    if (bt >= 1e10) {                       // fallback: full scan (≈never)
        double fb = 1e10; int fi = 0x7fffffff;
        for (int F = lane; F < NF; F += 64) {
            const double t = mt_eval_f64(F, faces, sx, sy, sz, ox, oy, oz, dx, dy, dz);
            if (t < fb || (t == fb && F < fi)) { fb = t; fi = F; }
        }
        for (int off = 32; off; off >>= 1) {
            const double t2 = __shfl_down(fb, off);
            const int    i2 = __shfl_down(fi, off);
            if (t2 < fb || (t2 == fb && i2 < fi)) { fb = t2; fi = i2; }
        }
        bt = __shfl(fb, 0);
        bi = __shfl(fi, 0);
    }

    const bool   hit = bt < 5.0;
    const double t0  = hit ? bt : 0.0;
    if (lane == 0) {
        out_tstart[r] = (float)t0;
        out_tend[r]   = hit ? (float)(t0 + 0.05) : 0.0f;
    }

    // ================= phase 2: walk (R8-identical, seq in LDS) ==========
    const double hpx = ox + t0 * dx, hpy = oy + t0 * dy, hpz = oz + t0 * dz;

    if (!hit) {
        for (int k = lane; k < S_MAX; k += 64) myseq[k] = -1;
    } else {
        int  tet   = bi >> 2;
        bool alive = true;

        int4 topo4 = ((const int4*)topo)[tet];
        const double* rec = winv + 12 * (size_t)tet;
        double v0x = rec[0], v0y = rec[1], v0z = rec[2];
        double i0 = rec[3], i1 = rec[4],  i2 = rec[5];
        double i3 = rec[6], i4 = rec[7],  i5 = rec[8];
        double i6 = rec[9], i7 = rec[10], i8 = rec[11];

        double wb0, wb1, wb2, wb3, wd0, wd1, wd2, wd3;
        {
            const double bx = hpx - v0x, by = hpy - v0y, bz = hpz - v0z;
            wb1 = i0 * bx + i1 * by + i2 * bz;
            wb2 = i3 * bx + i4 * by + i5 * bz;
            wb3 = i6 * bx + i7 * by + i8 * bz;
            wd1 = i0 * dx + i1 * dy + i2 * dz;
            wd2 = i3 * dx + i4 * dy + i5 * dz;
            wd3 = i6 * dx + i7 * dy + i8 * dz;
            wb0 = 1.0 - (wb1 + wb2 + wb3);
            wd0 = -(wd1 + wd2 + wd3);
        }

        int k0 = 0;
        while (k0 < S_MAX) {
            const int kk = k0 + lane;
            bool p = false;
            if (kk < S_MAX) {
                const double toff = (double)kk * STEPD + 1e-4;
                const double a0 = wb0 + toff * wd0;
                const double a1 = wb1 + toff * wd1;
                const double a2 = wb2 + toff * wd2;
                const double a3 = wb3 + toff * wd3;
                const double mn = fmin(fmin(a0, a1), fmin(a2, a3));
                p = (mn + 1e-6 >= GUARD);
            }
            const unsigned long long bad = __ballot(kk < S_MAX && !p);
            const int nvalid = min(S_MAX - k0, 64);
            const int evt = (bad == 0ull) ? nvalid : (__ffsll(bad) - 1);

            if (lane < evt) myseq[kk] = (short)tet;
            k0 += evt;
            if (evt == nvalid) continue;

            // ---- exact event at sample k0 (uniform; R8-identical) ----
            const double toff = (double)k0 * STEPD + 1e-4;
            const double px = hpx + toff * dx;
            const double py = hpy + toff * dy;
            const double pz = hpz + toff * dz;

            double b1 = px - v0x, b2 = py - v0y, b3 = pz - v0z;
            double w1 = i0 * b1 + i1 * b2 + i2 * b3;
            double w2 = i3 * b1 + i4 * b2 + i5 * b3;
            double w3 = i6 * b1 + i7 * b2 + i8 * b3;
            double w0 = 1.0 - (w1 + w2 + w3);
            bool inside = (w0 >= -1e-6) && (w1 >= -1e-6) && (w2 >= -1e-6) && (w3 >= -1e-6);

            int it = 0;
            bool moved = false;
            while (!inside && it < 3) {
                int    jm = 0;
                double wb = w0;
                if (w1 < wb) { wb = w1; jm = 1; }
                if (w2 < wb) { wb = w2; jm = 2; }
                if (w3 < wb) { wb = w3; jm = 3; }
                const int nb = (jm == 0) ? topo4.w : (jm == 1) ? topo4.z :
                               (jm == 2) ? topo4.y : topo4.x;
                if (nb < 0) { alive = false; break; }
                tet = nb;
                moved = true;
                rec = winv + 12 * (size_t)tet;
                topo4 = ((const int4*)topo)[tet];
                v0x = rec[0]; v0y = rec[1]; v0z = rec[2];
                i0 = rec[3]; i1 = rec[4];  i2 = rec[5];
                i3 = rec[6]; i4 = rec[7];  i5 = rec[8];
                i6 = rec[9]; i7 = rec[10]; i8 = rec[11];
                b1 = px - v0x; b2 = py - v0y; b3 = pz - v0z;
                w1 = i0 * b1 + i1 * b2 + i2 * b3;
                w2 = i3 * b1 + i4 * b2 + i5 * b3;
                w3 = i6 * b1 + i7 * b2 + i8 * b3;
                w0 = 1.0 - (w1 + w2 + w3);
                inside = (w0 >= -1e-6) && (w1 >= -1e-6) && (w2 >= -1e-6) && (w3 >= -1e-6);
                ++it;
            }
            if (!alive) break;

            if (lane == 0) myseq[k0] = inside ? (short)tet : (short)-1;
            ++k0;

            if (moved) {
                const double bx = hpx - v0x, by = hpy - v0y, bz = hpz - v0z;
                wb1 = i0 * bx + i1 * by + i2 * bz;
                wb2 = i3 * bx + i4 * by + i5 * bz;
                wb3 = i6 * bx + i7 * by + i8 * bz;
                wd1 = i0 * dx + i1 * dy + i2 * dz;
                wd2 = i3 * dx + i4 * dy + i5 * dz;
                wd3 = i6 * dx + i7 * dy + i8 * dz;
                wb0 = 1.0 - (wb1 + wb2 + wb3);
                wd0 = -(wd1 + wd2 + wd3);
            }
        }
        for (int k = k0 + lane; k < S_MAX; k += 64) myseq[k] = -1;
    }

    // ================= phase 3: emit (R8-identical expressions) ==========
    for (int k = lane; k < S_MAX; k += 64) {
        const size_t idx = (size_t)r * S_MAX + k;
        const int tk = (int)myseq[k];
        if (tk < 0) {
            out_rayidx[idx] = -1.0f;
            out_tetidx[idx] = -1.0f;
            ((float4*)out_bary)[idx] = make_float4(0.0f, 0.0f, 0.0f, 0.0f);
            out_pos[idx * 3 + 0] = 0.0f;
            out_pos[idx * 3 + 1] = 0.0f;
            out_pos[idx * 3 + 2] = 0.0f;
            continue;
        }
        const double toff = (double)k * STEPD + 1e-4;
        const double px = hpx + toff * dx;
        const double py = hpy + toff * dy;
        const double pz = hpz + toff * dz;

        const double* rec2 = winv + 12 * (size_t)tk;
        const double b1 = px - rec2[0], b2 = py - rec2[1], b3 = pz - rec2[2];
        const double w1 = rec2[3] * b1 + rec2[4]  * b2 + rec2[5]  * b3;
        const double w2 = rec2[6] * b1 + rec2[7]  * b2 + rec2[8]  * b3;
        const double w3 = rec2[9] * b1 + rec2[10] * b2 + rec2[11] * b3;
        const double w0 = 1.0 - (w1 + w2 + w3);

        out_rayidx[idx] = (float)r;
        out_tetidx[idx] = (float)tk;
        ((float4*)out_bary)[idx] = make_float4((float)w0, (float)w1, (float)w2, (float)w3);
        out_pos[idx * 3 + 0] = (float)px;
        out_pos[idx * 3 + 1] = (float)py;
        out_pos[idx * 3 + 2] = (float)pz;
    }
}

extern "C" void kernel_launch(void* const* d_in, const int* in_sizes, int n_in,
                              void* d_out, int out_size, void* d_ws, size_t ws_size,
                              hipStream_t stream) {
    const float* verts  = (const float*)d_in[0];
    const float* ro     = (const float*)d_in[1];
    const float* rd     = (const float*)d_in[2];
    const int*   tetras = (const int*)d_in[3];
    const int*   faces  = (const int*)d_in[4];
    const int*   topo   = (const int*)d_in[5];

    const int NV = in_sizes[0] / 3;
    const int R  = in_sizes[1] / 3;
    const int NT = in_sizes[3] / 4;
    const int NF = in_sizes[4] / 3;
    const int S  = S_MAX;

    // ws: winv f64[12*NT]
    double* winv = (double*)d_ws;

    float* out        = (float*)d_out;
    float* out_rayidx = out;
    float* out_tetidx = out + (size_t)R * S;
    float* out_bary   = out + (size_t)2 * R * S;
    float* out_tstart = out + (size_t)6 * R * S;
    float* out_tend   = out_tstart + R;
    float* out_pos    = out_tend + R;

    prep_kernel<<<(NT + 255) / 256, 256, 0, stream>>>(verts, tetras, winv, NT);
    fused_kernel<<<(R + 3) / 4, 256, 0, stream>>>(
        verts, ro, rd, faces, topo, winv,
        out_rayidx, out_tetidx, out_bary, out_tstart, out_tend, out_pos,
        NV, NF, R);
}

// Round 10
// 81.982 us; speedup vs baseline: 3.6547x; 1.0174x over previous
//
#include <hip/hip_runtime.h>

#define S_MAX 128
#define NV_MAX 729
#define STEPD (0.05 / 128.0)
#define GUARD 1e-12

// ---------------------------------------------------------------------------
// Exact f64 Moller-Trumbore for face F (round-3-identical). Returns t or 1e10.
// ---------------------------------------------------------------------------
static __device__ __forceinline__ double mt_eval_f64(
    int F, const int* __restrict__ faces,
    const float* sx, const float* sy, const float* sz,
    double ox, double oy, double oz,
    double dx, double dy, double dz)
{
    const int i0 = faces[3 * F + 0];
    const int i1 = faces[3 * F + 1];
    const int i2 = faces[3 * F + 2];
    const double p0x = (double)sx[i0], p0y = (double)sy[i0], p0z = (double)sz[i0];
    const double e1x = (double)sx[i1] - p0x, e1y = (double)sy[i1] - p0y, e1z = (double)sz[i1] - p0z;
    const double e2x = (double)sx[i2] - p0x, e2y = (double)sy[i2] - p0y, e2z = (double)sz[i2] - p0z;
    const double hx = dy * e2z - dz * e2y;
    const double hy = dz * e2x - dx * e2z;
    const double hz = dx * e2y - dy * e2x;
    const double a  = e1x * hx + e1y * hy + e1z * hz;
    const bool oka = fabs(a) > 1e-9;
    const double f  = 1.0 / (oka ? a : 1e-9);
    const double s0 = ox - p0x, s1 = oy - p0y, s2 = oz - p0z;
    const double u  = f * (s0 * hx + s1 * hy + s2 * hz);
    const double qx = s1 * e1z - s2 * e1y;
    const double qy = s2 * e1x - s0 * e1z;
    const double qz = s0 * e1y - s1 * e1x;
    const double v  = f * (dx * qx + dy * qy + dz * qz);
    double t        = f * (e2x * qx + e2y * qy + e2z * qz);
    const bool ok = oka && (u >= 0.0) && (u <= 1.0) && (v >= 0.0) &&
                    (u + v <= 1.0) && (t > 1e-6);
    return ok ? t : 1e10;
}

// ---------------------------------------------------------------------------
// Single fused kernel, one wave per ray:
//   phase 1: first hit (R9-identical)
//   phase 2: ballot walk with INLINE emission — segment samples are emitted
//            from the wave-uniform {v0, inv} registers with the R9 phase-3
//            matvec expressions (bit-identical); the per-tet inverse is built
//            on demand with prep_kernel-identical expressions (bit-identical).
// No workspace, no second launch.
// ---------------------------------------------------------------------------
__global__ __launch_bounds__(256) void fused_kernel(
    const float* __restrict__ verts,
    const float* __restrict__ ro,
    const float* __restrict__ rd,
    const int*   __restrict__ faces,
    const int*   __restrict__ tetras,
    const int*   __restrict__ topo,
    float* __restrict__ out_rayidx,
    float* __restrict__ out_tetidx,
    float* __restrict__ out_bary,
    float* __restrict__ out_tstart,
    float* __restrict__ out_tend,
    float* __restrict__ out_pos,
    int NV, int NF, int R)
{
    __shared__ float sx[NV_MAX], sy[NV_MAX], sz[NV_MAX];
    __shared__ float red[256];
    __shared__ float s_zmin, s_zmax, s_marg;

    const int tid = threadIdx.x;
    for (int i = tid; i < NV; i += 256) {
        sx[i] = verts[3 * i + 0];
        sy[i] = verts[3 * i + 1];
        sz[i] = verts[3 * i + 2];
    }
    __syncthreads();

    // ---- mesh bounds (block-uniform; R9-identical) ----
    float zmin = 1e9f, zmax = -1e9f, dev = 0.0f;
    for (int i = tid; i < NV; i += 256) {
        const float x = sx[i], y = sy[i], z = sz[i];
        if (i % 9 == 0) { zmin = fminf(zmin, z); zmax = fmaxf(zmax, z); }
        dev = fmaxf(dev, fabsf(x - rintf(x * 8.0f) * 0.125f));
        dev = fmaxf(dev, fabsf(y - rintf(y * 8.0f) * 0.125f));
    }
    red[tid] = zmin; __syncthreads();
    for (int s = 128; s; s >>= 1) { if (tid < s) red[tid] = fminf(red[tid], red[tid + s]); __syncthreads(); }
    if (tid == 0) s_zmin = red[0];
    __syncthreads();
    red[tid] = zmax; __syncthreads();
    for (int s = 128; s; s >>= 1) { if (tid < s) red[tid] = fmaxf(red[tid], red[tid + s]); __syncthreads(); }
    if (tid == 0) s_zmax = red[0];
    __syncthreads();
    red[tid] = dev; __syncthreads();
    for (int s = 128; s; s >>= 1) { if (tid < s) red[tid] = fmaxf(red[tid], red[tid + s]); __syncthreads(); }
    if (tid == 0) s_marg = red[0] + 1e-5f;
    __syncthreads();

    const int wv = tid >> 6, lane = tid & 63;
    const int r = blockIdx.x * 4 + wv;
    if (r >= R) return;

    const double ox = (double)ro[3 * r + 0], oy = (double)ro[3 * r + 1], oz = (double)ro[3 * r + 2];
    const double dx = (double)rd[3 * r + 0], dy = (double)rd[3 * r + 1], dz = (double)rd[3 * r + 2];

    // ================= phase 1: first hit (R9-identical) =================
    int ncand = 0, ixlo = 0, iylo = 0, ny = 1;
    if (dz > 0.0) {
        const double t_lo = ((double)s_zmin - oz) / dz;
        const double t_hi = ((double)s_zmax - oz) / dz;
        const double marg = (double)s_marg + 1e-9;
        const double xa = ox + t_lo * dx, xb = ox + t_hi * dx;
        const double ya = oy + t_lo * dy, yb = oy + t_hi * dy;
        const double xlo = fmin(xa, xb) - marg, xhi = fmax(xa, xb) + marg;
        const double ylo = fmin(ya, yb) - marg, yhi = fmax(ya, yb) + marg;
        const int ix0 = max(0, (int)floor(xlo * 8.0)), ix1 = min(7, (int)floor(xhi * 8.0));
        const int iy0 = max(0, (int)floor(ylo * 8.0)), iy1 = min(7, (int)floor(yhi * 8.0));
        if (ix0 <= ix1 && iy0 <= iy1) {
            ixlo = ix0; iylo = iy0;
            ny = iy1 - iy0 + 1;
            ncand = (ix1 - ix0 + 1) * ny * 24;
        }
    }

    double bt = 1e10;
    int    bi = 0x7fffffff;
    for (int c = lane; c < ncand; c += 64) {
        const int cell = c / 24, fk = c - cell * 24;
        const int cx = cell / ny, cy = cell - cx * ny;
        const int F = ((ixlo + cx) * 64 + (iylo + cy) * 8) * 24 + fk;
        const double t = mt_eval_f64(F, faces, sx, sy, sz, ox, oy, oz, dx, dy, dz);
        if (t < bt || (t == bt && F < bi)) { bt = t; bi = F; }
    }
    for (int off = 32; off; off >>= 1) {
        const double t2 = __shfl_down(bt, off);
        const int    i2 = __shfl_down(bi, off);
        if (t2 < bt || (t2 == bt && i2 < bi)) { bt = t2; bi = i2; }
    }
    bt = __shfl(bt, 0);
    bi = __shfl(bi, 0);
    if (bt >= 1e10) {                       // fallback: full scan (≈never)
        double fb = 1e10; int fi = 0x7fffffff;
        for (int F = lane; F < NF; F += 64) {
            const double t = mt_eval_f64(F, faces, sx, sy, sz, ox, oy, oz, dx, dy, dz);
            if (t < fb || (t == fb && F < fi)) { fb = t; fi = F; }
        }
        for (int off = 32; off; off >>= 1) {
            const double t2 = __shfl_down(fb, off);
            const int    i2 = __shfl_down(fi, off);
            if (t2 < fb || (t2 == fb && i2 < fi)) { fb = t2; fi = i2; }
        }
        bt = __shfl(fb, 0);
        bi = __shfl(fi, 0);
    }

    const bool   hit = bt < 5.0;
    const double t0  = hit ? bt : 0.0;
    if (lane == 0) {
        out_tstart[r] = (float)t0;
        out_tend[r]   = hit ? (float)(t0 + 0.05) : 0.0f;
    }

    const double hpx = ox + t0 * dx, hpy = oy + t0 * dy, hpz = oz + t0 * dz;
    const size_t rbase = (size_t)r * S_MAX;

    // invalid-sample writer (R9 emit invalid pattern)
    auto emit_invalid = [&](int k) {
        const size_t idx = rbase + k;
        out_rayidx[idx] = -1.0f;
        out_tetidx[idx] = -1.0f;
        ((float4*)out_bary)[idx] = make_float4(0.0f, 0.0f, 0.0f, 0.0f);
        out_pos[idx * 3 + 0] = 0.0f;
        out_pos[idx * 3 + 1] = 0.0f;
        out_pos[idx * 3 + 2] = 0.0f;
    };

    if (!hit) {
        for (int k = lane; k < S_MAX; k += 64) emit_invalid(k);
        return;
    }

    // ================= phase 2: walk + inline emit =======================
    int  tet   = bi >> 2;
    bool alive = true;

    const int4* tets4 = (const int4*)tetras;
    const int4* topo16 = (const int4*)topo;

    int4 topo4;
    double v0x, v0y, v0z;
    double i0, i1, i2, i3, i4, i5, i6, i7, i8;

    // prep_kernel-identical inverse build (bit-identical i*, v0*)
    auto build_inv = [&]() {
        const int4 tv = tets4[tet];
        v0x = (double)sx[tv.x]; v0y = (double)sy[tv.x]; v0z = (double)sz[tv.x];
        const double m11 = (double)sx[tv.y] - v0x, m21 = (double)sy[tv.y] - v0y, m31 = (double)sz[tv.y] - v0z;
        const double m12 = (double)sx[tv.z] - v0x, m22 = (double)sy[tv.z] - v0y, m32 = (double)sz[tv.z] - v0z;
        const double m13 = (double)sx[tv.w] - v0x, m23 = (double)sy[tv.w] - v0y, m33 = (double)sz[tv.w] - v0z;
        const double A = m22 * m33 - m23 * m32;
        const double B = m21 * m33 - m23 * m31;
        const double C = m21 * m32 - m22 * m31;
        const double det = m11 * A - m12 * B + m13 * C;
        const double rcp = 1.0 / det;
        i0 = A * rcp;  i1 = (m13 * m32 - m12 * m33) * rcp;  i2 = (m12 * m23 - m13 * m22) * rcp;
        i3 = -B * rcp; i4 = (m11 * m33 - m13 * m31) * rcp;  i5 = (m13 * m21 - m11 * m23) * rcp;
        i6 = C * rcp;  i7 = (m12 * m31 - m11 * m32) * rcp;  i8 = (m11 * m22 - m12 * m21) * rcp;
    };

    topo4 = topo16[tet];
    build_inv();

    double wb0, wb1, wb2, wb3, wd0, wd1, wd2, wd3;
    auto build_affine = [&]() {
        const double bx = hpx - v0x, by = hpy - v0y, bz = hpz - v0z;
        wb1 = i0 * bx + i1 * by + i2 * bz;
        wb2 = i3 * bx + i4 * by + i5 * bz;
        wb3 = i6 * bx + i7 * by + i8 * bz;
        wd1 = i0 * dx + i1 * dy + i2 * dz;
        wd2 = i3 * dx + i4 * dy + i5 * dz;
        wd3 = i6 * dx + i7 * dy + i8 * dz;
        wb0 = 1.0 - (wb1 + wb2 + wb3);
        wd0 = -(wd1 + wd2 + wd3);
    };
    build_affine();

    int k0 = 0;
    while (k0 < S_MAX) {
        const int kk = k0 + lane;
        bool p = false;
        if (kk < S_MAX) {
            const double toff = (double)kk * STEPD + 1e-4;
            const double a0 = wb0 + toff * wd0;
            const double a1 = wb1 + toff * wd1;
            const double a2 = wb2 + toff * wd2;
            const double a3 = wb3 + toff * wd3;
            const double mn = fmin(fmin(a0, a1), fmin(a2, a3));
            p = (mn + 1e-6 >= GUARD);
        }
        const unsigned long long bad = __ballot(kk < S_MAX && !p);
        const int nvalid = min(S_MAX - k0, 64);
        const int evt = (bad == 0ull) ? nvalid : (__ffsll(bad) - 1);

        if (lane < evt) {
            // inline emit (R9 phase-3 expressions, register-sourced inverse)
            const double toff = (double)kk * STEPD + 1e-4;
            const double px = hpx + toff * dx;
            const double py = hpy + toff * dy;
            const double pz = hpz + toff * dz;
            const double b1 = px - v0x, b2 = py - v0y, b3 = pz - v0z;
            const double w1 = i0 * b1 + i1 * b2 + i2 * b3;
            const double w2 = i3 * b1 + i4 * b2 + i5 * b3;
            const double w3 = i6 * b1 + i7 * b2 + i8 * b3;
            const double w0 = 1.0 - (w1 + w2 + w3);
            const size_t idx = rbase + kk;
            out_rayidx[idx] = (float)r;
            out_tetidx[idx] = (float)tet;
            ((float4*)out_bary)[idx] = make_float4((float)w0, (float)w1, (float)w2, (float)w3);
            out_pos[idx * 3 + 0] = (float)px;
            out_pos[idx * 3 + 1] = (float)py;
            out_pos[idx * 3 + 2] = (float)pz;
        }
        k0 += evt;
        if (evt == nvalid) continue;

        // ---- exact event at sample k0 (uniform; R9-identical decisions) ----
        const double toff = (double)k0 * STEPD + 1e-4;
        const double px = hpx + toff * dx;
        const double py = hpy + toff * dy;
        const double pz = hpz + toff * dz;

        double b1 = px - v0x, b2 = py - v0y, b3 = pz - v0z;
        double w1 = i0 * b1 + i1 * b2 + i2 * b3;
        double w2 = i3 * b1 + i4 * b2 + i5 * b3;
        double w3 = i6 * b1 + i7 * b2 + i8 * b3;
        double w0 = 1.0 - (w1 + w2 + w3);
        bool inside = (w0 >= -1e-6) && (w1 >= -1e-6) && (w2 >= -1e-6) && (w3 >= -1e-6);

        int it = 0;
        bool moved = false;
        while (!inside && it < 3) {
            int    jm = 0;
            double wb = w0;
            if (w1 < wb) { wb = w1; jm = 1; }
            if (w2 < wb) { wb = w2; jm = 2; }
            if (w3 < wb) { wb = w3; jm = 3; }
            const int nb = (jm == 0) ? topo4.w : (jm == 1) ? topo4.z :
                           (jm == 2) ? topo4.y : topo4.x;
            if (nb < 0) { alive = false; break; }
            tet = nb;
            moved = true;
            topo4 = topo16[tet];
            build_inv();
            b1 = px - v0x; b2 = py - v0y; b3 = pz - v0z;
            w1 = i0 * b1 + i1 * b2 + i2 * b3;
            w2 = i3 * b1 + i4 * b2 + i5 * b3;
            w3 = i6 * b1 + i7 * b2 + i8 * b3;
            w0 = 1.0 - (w1 + w2 + w3);
            inside = (w0 >= -1e-6) && (w1 >= -1e-6) && (w2 >= -1e-6) && (w3 >= -1e-6);
            ++it;
        }
        if (!alive) break;

        if (lane == 0) {
            if (inside) {
                const size_t idx = rbase + k0;
                out_rayidx[idx] = (float)r;
                out_tetidx[idx] = (float)tet;
                ((float4*)out_bary)[idx] = make_float4((float)w0, (float)w1, (float)w2, (float)w3);
                out_pos[idx * 3 + 0] = (float)px;
                out_pos[idx * 3 + 1] = (float)py;
                out_pos[idx * 3 + 2] = (float)pz;
            } else {
                emit_invalid(k0);
            }
        }
        ++k0;

        if (moved) build_affine();
    }
    for (int k = k0 + lane; k < S_MAX; k += 64) emit_invalid(k);
}

extern "C" void kernel_launch(void* const* d_in, const int* in_sizes, int n_in,
                              void* d_out, int out_size, void* d_ws, size_t ws_size,
                              hipStream_t stream) {
    const float* verts  = (const float*)d_in[0];
    const float* ro     = (const float*)d_in[1];
    const float* rd     = (const float*)d_in[2];
    const int*   tetras = (const int*)d_in[3];
    const int*   faces  = (const int*)d_in[4];
    const int*   topo   = (const int*)d_in[5];

    const int NV = in_sizes[0] / 3;
    const int R  = in_sizes[1] / 3;
    const int NF = in_sizes[4] / 3;
    const int S  = S_MAX;

    float* out        = (float*)d_out;
    float* out_rayidx = out;
    float* out_tetidx = out + (size_t)R * S;
    float* out_bary   = out + (size_t)2 * R * S;
    float* out_tstart = out + (size_t)6 * R * S;
    float* out_tend   = out_tstart + R;
    float* out_pos    = out_tend + R;

    fused_kernel<<<(R + 3) / 4, 256, 0, stream>>>(
        verts, ro, rd, faces, tetras, topo,
        out_rayidx, out_tetidx, out_bary, out_tstart, out_tend, out_pos,
        NV, NF, R);
}